// Round 11
// baseline (532.916 us; speedup 1.0000x reference)
//
#include <hip/hip_runtime.h>
#include <stdint.h>

#define N_TOK 16384
#define DIM   1024
#define NEXP  8
#define FF    2048
#define CAP   2560
#define NSLOT (NEXP*CAP)   // 20480

using f32x4  = __attribute__((ext_vector_type(4))) float;
using bf16x8 = __attribute__((ext_vector_type(8))) short;

__device__ __forceinline__ unsigned short f2bf(float f){
  union { float f; unsigned u; } c; c.f = f;
  unsigned u = c.u + 0x7FFFu + ((c.u >> 16) & 1u);   // RNE
  return (unsigned short)(u >> 16);
}
__device__ __forceinline__ float bf2f(unsigned short h){
  union { unsigned u; float f; } c; c.u = ((unsigned)h) << 16; return c.f;
}

__device__ __forceinline__ void gld16(const unsigned short* g, unsigned short* l){
  __builtin_amdgcn_global_load_lds((__attribute__((address_space(1))) void*)(void*)g,
                                   (__attribute__((address_space(3))) void*)l,
                                   16, 0, 0);
}

#define HBAR __builtin_amdgcn_s_barrier()
#define LG0  asm volatile("s_waitcnt lgkmcnt(0)" ::: "memory")

// ---------------- router: fp64 logits/softmax; aux partial-sums fused ----------------
__global__ __launch_bounds__(256) void k_router(
    const float* __restrict__ x, const float* __restrict__ gate_w,
    int* __restrict__ topidx, float* __restrict__ topw,
    float* __restrict__ aux_part)            // [64 banks][8]
{
  __shared__ float gwT[NEXP][DIM];
  int tid = threadIdx.x;
  for (int i = tid; i < DIM*NEXP/4; i += 256){   // vectorized fill: [DIM][NEXP] f32
    float4 v = ((const float4*)gate_w)[i];
    int b = i*4;                                  // elem = d*8+e; 4 consecutive e, same d
    int d = b >> 3, e0 = b & 7;
    gwT[e0+0][d] = v.x; gwT[e0+1][d] = v.y; gwT[e0+2][d] = v.z; gwT[e0+3][d] = v.w;
  }
  __syncthreads();
  int wave = tid >> 6, lane = tid & 63;
  int t = blockIdx.x * 4 + wave;
  const float* xr = x + (size_t)t * DIM;
  double acc[NEXP];
  #pragma unroll
  for (int e = 0; e < NEXP; e++) acc[e] = 0.0;
  for (int j = 0; j < DIM/64; j++){
    double xv = (double)xr[lane + 64*j];
    #pragma unroll
    for (int e = 0; e < NEXP; e++) acc[e] += xv * (double)gwT[e][lane + 64*j];
  }
  #pragma unroll
  for (int off = 32; off >= 1; off >>= 1){
    #pragma unroll
    for (int e = 0; e < NEXP; e++) acc[e] += __shfl_xor(acc[e], off, 64);
  }
  if (lane == 0){
    double m = acc[0];
    #pragma unroll
    for (int e = 1; e < NEXP; e++) m = fmax(m, acc[e]);
    double p[NEXP], Z = 0.0;
    #pragma unroll
    for (int e = 0; e < NEXP; e++){ p[e] = exp(acc[e] - m); Z += p[e]; }
    double invZ = 1.0 / Z;
    #pragma unroll
    for (int e = 0; e < NEXP; e++) p[e] *= invZ;
    // aux partials: spread contention over 64 banks (per-wave atomic)
    float* bank = aux_part + ((blockIdx.x*4 + wave) & 63) * NEXP;
    #pragma unroll
    for (int e = 0; e < NEXP; e++) atomicAdd(&bank[e], (float)p[e]);
    int i0 = 0; double p0 = p[0];
    #pragma unroll
    for (int e = 1; e < NEXP; e++) if (p[e] > p0){ p0 = p[e]; i0 = e; }
    int i1 = (i0 == 0) ? 1 : 0; double p1 = p[i1];
    #pragma unroll
    for (int e = 0; e < NEXP; e++) if (e != i0 && p[e] > p1){ p1 = p[e]; i1 = e; }
    double s = p0 + p1;
    topidx[t*2+0] = i0; topidx[t*2+1] = i1;
    topw [t*2+0] = (float)(p0/s); topw[t*2+1] = (float)(p1/s);
  }
}

// ---------------- ordered capacity scan + final aux from partials ----------------
__global__ __launch_bounds__(1024) void k_scan(
    const int* __restrict__ topidx, const float* __restrict__ aux_part,
    int* __restrict__ slot_token, int* __restrict__ tok_slots,
    float* __restrict__ aux_out)
{
  __shared__ int sc[1024][NEXP];
  const int t = threadIdx.x;
  const int base_i = t * 32;
  int ids[32];
  #pragma unroll
  for (int j = 0; j < 32; j++) ids[j] = topidx[base_i + j];
  int b[NEXP];
  #pragma unroll
  for (int e = 0; e < NEXP; e++) b[e] = 0;
  #pragma unroll
  for (int j = 0; j < 32; j++){
    #pragma unroll
    for (int e = 0; e < NEXP; e++) if (ids[j] == e) b[e]++;
  }
  #pragma unroll
  for (int e = 0; e < NEXP; e++) sc[t][e] = b[e];
  __syncthreads();
  for (int off = 1; off < 1024; off <<= 1){
    int tmp[NEXP];
    #pragma unroll
    for (int e = 0; e < NEXP; e++) tmp[e] = (t >= off) ? sc[t-off][e] : 0;
    __syncthreads();
    #pragma unroll
    for (int e = 0; e < NEXP; e++) sc[t][e] += tmp[e];
    __syncthreads();
  }
  int myb[NEXP];
  #pragma unroll
  for (int e = 0; e < NEXP; e++) myb[e] = sc[t][e] - b[e];
  if (t == 0){
    float aux = 0.f;
    #pragma unroll
    for (int e = 0; e < NEXP; e++){
      float P = 0.f;
      for (int w = 0; w < 64; w++) P += aux_part[w*NEXP + e];
      P /= (float)N_TOK;
      float f = (float)sc[1023][e] / ((float)(N_TOK*2) + 1e-9f);
      aux += f * P;
    }
    aux_out[0] = (float)NEXP * aux * 0.01f;
  }
  #pragma unroll
  for (int j = 0; j < 32; j++){
    int slot = -1;
    #pragma unroll
    for (int e = 0; e < NEXP; e++){
      if (ids[j] == e){
        int r = myb[e]; myb[e] = r + 1;
        if (r < CAP){
          slot = e*CAP + r;
          slot_token[slot] = (base_i + j) >> 1;
        }
      }
    }
    tok_slots[base_i + j] = slot;
  }
}

// ---------------- merged transpose+cast: all three weights in one launch ----------------
__global__ __launch_bounds__(256) void k_tcv_all(
    const float* __restrict__ wg, const float* __restrict__ wu, const float* __restrict__ wd,
    unsigned short* __restrict__ B1, unsigned short* __restrict__ wdT)
{
  __shared__ float tt[64][65];
  const int z = blockIdx.z, mode = z >> 3, e = z & 7;
  const float* in; unsigned short* out; int R, C, ct, rt;
  if (mode < 2){
    in  = (mode == 0 ? wg : wu) + (size_t)e * DIM * FF;
    out = B1 + (size_t)e * 2 * FF * DIM;
    R = DIM; C = FF; ct = blockIdx.x; rt = blockIdx.y;      // 32 x 16
  } else {
    in  = wd + (size_t)e * FF * DIM;
    out = wdT + (size_t)e * DIM * FF;
    R = FF; C = DIM; ct = blockIdx.y; rt = blockIdx.x;      // 16 x 32
  }
  const int c0 = ct * 64, r0 = rt * 64;
  const int tid = threadIdx.x;
  #pragma unroll
  for (int i = 0; i < 4; i++){
    int idx = i*256 + tid;
    int row = idx >> 4, c4 = idx & 15;
    float4 v = *(const float4*)(in + (size_t)(r0 + row)*C + c0 + c4*4);
    tt[c4*4+0][row] = v.x; tt[c4*4+1][row] = v.y;
    tt[c4*4+2][row] = v.z; tt[c4*4+3][row] = v.w;
  }
  __syncthreads();
  #pragma unroll
  for (int i = 0; i < 2; i++){
    int cl = i*32 + (tid >> 3);
    int rs = (tid & 7) * 8;
    int c  = c0 + cl;
    int orow = (mode == 0) ? ((c>>4)*32 + (c&15))
             : (mode == 1) ? ((c>>4)*32 + 16 + (c&15))
             : c;
    unsigned long long pk0 = 0, pk1 = 0;
    #pragma unroll
    for (int j = 0; j < 4; j++) pk0 |= (unsigned long long)f2bf(tt[cl][rs+j]) << (16*j);
    #pragma unroll
    for (int j = 0; j < 4; j++) pk1 |= (unsigned long long)f2bf(tt[cl][rs+4+j]) << (16*j);
    unsigned long long* dst = (unsigned long long*)(out + (size_t)orow*R + r0 + rs);
    dst[0] = pk0; dst[1] = pk1;
  }
}

// ---------------- gather x rows into dispatched bf16 ----------------
__global__ __launch_bounds__(256) void k_gather(
    const float* __restrict__ x, const int* __restrict__ slot_token,
    unsigned short* __restrict__ disp)
{
  const int s = blockIdx.x;
  const int t = slot_token[s];
  const int tid = threadIdx.x;
  unsigned long long pk = 0ull;
  if (t >= 0){
    float4 v = *(const float4*)(x + (size_t)t*DIM + tid*4);
    pk =  (unsigned long long)f2bf(v.x)
       | ((unsigned long long)f2bf(v.y) << 16)
       | ((unsigned long long)f2bf(v.z) << 32)
       | ((unsigned long long)f2bf(v.w) << 48);
  }
  *(unsigned long long*)(disp + (size_t)s*DIM + tid*4) = pk;
}

// ================= ring-4 half-K 256x256 GEMM core (R8-proven schedule) =================
__device__ __forceinline__ void stg(const unsigned short* gsrc, int ldg,
                                    unsigned short* Lh, int wave, int lane){
  const int sl = (lane & 3) ^ ((lane >> 3) & 3);   // inverse-swizzled source slot
  #pragma unroll
  for (int j = 0; j < 2; j++){
    int bi = wave*2 + j;
    gld16(gsrc + (size_t)(bi*16 + (lane >> 2))*ldg + sl*8, Lh + bi*512);
  }
}
__device__ __forceinline__ bf16x8 frd(const unsigned short* Lh, int r, int g){
  return *(const bf16x8*)(Lh + r*32 + (((g ^ ((r >> 1) & 3))) << 3));
}
template<int MG>
__device__ __forceinline__ void mm16(f32x4 (&acc)[8][4], const bf16x8 (&a)[4], const bf16x8 (&b)[4]){
  #pragma unroll
  for (int i = 0; i < 4; i++)
    #pragma unroll
    for (int n = 0; n < 4; n++)
      acc[MG*4+i][n] = __builtin_amdgcn_mfma_f32_16x16x32_bf16(a[i], b[n], acc[MG*4+i][n], 0, 0, 0);
}

#define HALF_STEP(RS, DOSTG, VMW, ASRC, BSRC)                                   \
  {                                                                             \
    unsigned short* LA = lds + (RS)*16384;                                      \
    unsigned short* LB = LA + 8192;                                             \
    unsigned short* NS = lds + (((RS)+3)&3)*16384;                              \
    bf16x8 a[4], b[4];                                                          \
    _Pragma("unroll")                                                           \
    for (int i = 0; i < 4; i++) a[i] = frd(LA, wr*128 + i*16 + l15, g);         \
    _Pragma("unroll")                                                           \
    for (int n = 0; n < 4; n++) b[n] = frd(LB, wc*64 + n*16 + l15, g);          \
    if (DOSTG) stg(ASRC, LDG, NS, wave, lane);                                  \
    HBAR; LG0;                                                                  \
    __builtin_amdgcn_s_setprio(1);  mm16<0>(acc, a, b);                         \
    __builtin_amdgcn_s_setprio(0);                                              \
    HBAR;                                                                       \
    _Pragma("unroll")                                                           \
    for (int i = 0; i < 4; i++) a[i] = frd(LA, wr*128 + (4+i)*16 + l15, g);     \
    if (DOSTG) stg(BSRC, LDG, NS + 8192, wave, lane);                           \
    HBAR; LG0;                                                                  \
    __builtin_amdgcn_s_setprio(1);  mm16<1>(acc, a, b);                         \
    __builtin_amdgcn_s_setprio(0);                                              \
    if ((VMW) == 4) { asm volatile("s_waitcnt vmcnt(4)" ::: "memory"); }        \
    else if ((VMW) == 0) { asm volatile("s_waitcnt vmcnt(0)" ::: "memory"); }   \
    HBAR;                                                                       \
  }

// EPI 1: gemm1 (silu fused -> hidden). EPI 2: gemm2 K-split -> bf16 partial ks.
template<int KDIM, int LDG, int EPI>
__global__ __launch_bounds__(512, 2) void k_gemm8(
    const unsigned short* __restrict__ A,
    const unsigned short* __restrict__ B,
    unsigned short* __restrict__ Out0,
    unsigned short* __restrict__ Out1)
{
  constexpr int NH    = KDIM / 32;               // 32 halves
  constexpr int BROWS = (EPI == 1) ? 2*FF : DIM;
  constexpr int LDO   = (EPI == 1) ? FF : DIM;
  __shared__ unsigned short lds[65536];          // 128 KiB = 4 half-slots
  const int id = blockIdx.x;
  const int e  = id & 7;                          // XCD-chunked: expert per XCD
  int t  = id >> 3;
  int ks = 0;
  if (EPI == 2){ ks = t & 1; t >>= 1; }           // K-slice
  const int mt = t % 10, nt = t / 10;
  const int m0 = mt*256, n0 = nt*256;
  const unsigned short* Ab = A + ((size_t)e*CAP   + m0) * LDG + (size_t)ks*KDIM;
  const unsigned short* Bb = B + ((size_t)e*BROWS + n0) * LDG + (size_t)ks*KDIM;
  const int tid = threadIdx.x, wave = tid >> 6, lane = tid & 63;
  const int wr = wave >> 2, wc = wave & 3;        // 2M x 4N waves
  const int g = lane >> 4, l15 = lane & 15;

  f32x4 acc[8][4];
  const f32x4 z4 = {0.f,0.f,0.f,0.f};
  #pragma unroll
  for (int i = 0; i < 8; i++)
    #pragma unroll
    for (int n = 0; n < 4; n++) acc[i][n] = z4;

  stg(Ab,      LDG, lds + 0*16384,        wave, lane);
  stg(Bb,      LDG, lds + 0*16384 + 8192, wave, lane);
  stg(Ab + 32, LDG, lds + 1*16384,        wave, lane);
  stg(Bb + 32, LDG, lds + 1*16384 + 8192, wave, lane);
  stg(Ab + 64, LDG, lds + 2*16384,        wave, lane);
  stg(Bb + 64, LDG, lds + 2*16384 + 8192, wave, lane);
  asm volatile("s_waitcnt vmcnt(4)" ::: "memory");
  HBAR;

  for (int h = 0; h + 8 <= NH; h += 4){
    HALF_STEP(0, true, -1, Ab + (size_t)(h+3)*32, Bb + (size_t)(h+3)*32);
    HALF_STEP(1, true,  4, Ab + (size_t)(h+4)*32, Bb + (size_t)(h+4)*32);
    HALF_STEP(2, true, -1, Ab + (size_t)(h+5)*32, Bb + (size_t)(h+5)*32);
    HALF_STEP(3, true,  4, Ab + (size_t)(h+6)*32, Bb + (size_t)(h+6)*32);
  }
  HALF_STEP(0, true, -1, Ab + (size_t)(NH-1)*32, Bb + (size_t)(NH-1)*32);
  HALF_STEP(1, false, 0, Ab, Bb);
  HALF_STEP(2, false, -1, Ab, Bb);
  HALF_STEP(3, false, -1, Ab, Bb);

  if (EPI == 1){
    unsigned short* H = Out0 + ((size_t)e*CAP + m0 + wr*128) * (size_t)LDO;
    const int hc0 = (n0 + wc*64) >> 1;
    #pragma unroll
    for (int mf = 0; mf < 8; mf++)
      #pragma unroll
      for (int q = 0; q < 4; q++){
        int r = mf*16 + g*4 + q;
        #pragma unroll
        for (int p = 0; p < 2; p++){
          float gg = acc[mf][2*p][q], uu = acc[mf][2*p+1][q];
          float h = gg / (1.f + __expf(-gg)) * uu;
          H[(size_t)r*LDO + hc0 + p*16 + l15] = f2bf(h);
        }
      }
  } else {
    unsigned short* P = (ks ? Out1 : Out0);
    unsigned short* O = P + ((size_t)e*CAP + m0 + wr*128) * (size_t)LDO + n0 + wc*64;
    #pragma unroll
    for (int mf = 0; mf < 8; mf++)
      #pragma unroll
      for (int q = 0; q < 4; q++){
        int r = mf*16 + g*4 + q;
        #pragma unroll
        for (int n = 0; n < 4; n++)
          O[(size_t)r*LDO + n*16 + l15] = f2bf(acc[mf][n][q]);
      }
  }
}

// ---------------- combine: out[t] = sum_k w_k * (P0[slot_k] + P1[slot_k]) ----------------
__global__ __launch_bounds__(256) void k_combine(
    const unsigned short* __restrict__ P0, const unsigned short* __restrict__ P1,
    const int* __restrict__ tok_slots, const float* __restrict__ topw,
    float* __restrict__ out)
{
  const int t = blockIdx.x*2 + (threadIdx.x >> 7);
  const int tid = threadIdx.x & 127;
  const int s0 = tok_slots[t*2+0], s1 = tok_slots[t*2+1];
  const float w0 = topw[t*2+0], w1 = topw[t*2+1];
  float r[8];
  #pragma unroll
  for (int j = 0; j < 8; j++) r[j] = 0.f;
  if (s0 >= 0){
    bf16x8 v0 = *(const bf16x8*)(P0 + (size_t)s0*DIM + tid*8);
    bf16x8 v1 = *(const bf16x8*)(P1 + (size_t)s0*DIM + tid*8);
    #pragma unroll
    for (int j = 0; j < 8; j++)
      r[j] += w0 * (bf2f((unsigned short)v0[j]) + bf2f((unsigned short)v1[j]));
  }
  if (s1 >= 0){
    bf16x8 v0 = *(const bf16x8*)(P0 + (size_t)s1*DIM + tid*8);
    bf16x8 v1 = *(const bf16x8*)(P1 + (size_t)s1*DIM + tid*8);
    #pragma unroll
    for (int j = 0; j < 8; j++)
      r[j] += w1 * (bf2f((unsigned short)v0[j]) + bf2f((unsigned short)v1[j]));
  }
  float4* o = (float4*)(out + (size_t)t*DIM + tid*8);
  o[0] = make_float4(r[0], r[1], r[2], r[3]);
  o[1] = make_float4(r[4], r[5], r[6], r[7]);
}

extern "C" void kernel_launch(void* const* d_in, const int* in_sizes, int n_in,
                              void* d_out, int out_size, void* d_ws, size_t ws_size,
                              hipStream_t stream)
{
  const float* x      = (const float*)d_in[0];
  const float* gate_w = (const float*)d_in[1];
  const float* w_gate = (const float*)d_in[2];
  const float* w_up   = (const float*)d_in[3];
  const float* w_down = (const float*)d_in[4];
  float* out = (float*)d_out;

  uint8_t* ws = (uint8_t*)d_ws;
  int*   topidx       = (int*)ws;               ws += (size_t)N_TOK*2*4;
  float* topw         = (float*)ws;             ws += (size_t)N_TOK*2*4;
  int*   slot_token   = (int*)ws;               ws += (size_t)NSLOT*4;
  int*   tok_slots    = (int*)ws;               ws += (size_t)N_TOK*2*4;
  float* aux_part     = (float*)ws;             ws += 64*NEXP*4;
  unsigned short* disp   = (unsigned short*)ws; ws += (size_t)NSLOT*DIM*2;     // P0 aliases after gemm1
  unsigned short* hidden = (unsigned short*)ws; ws += (size_t)NSLOT*FF*2;
  unsigned short* B1     = (unsigned short*)ws; ws += (size_t)NEXP*2*FF*DIM*2; // P1 aliases after gemm1
  unsigned short* wdT    = (unsigned short*)ws; ws += (size_t)NEXP*DIM*FF*2;
  size_t need = (size_t)(ws - (uint8_t*)d_ws);
  if (ws_size < need) return;
  unsigned short* P0 = disp;   // dead after gemm1 consumes it
  unsigned short* P1 = B1;     // dead after gemm1 consumes it (67 MB >= 42 MB)

  hipMemsetAsync(slot_token, 0xFF, (size_t)NSLOT * sizeof(int), stream);
  hipMemsetAsync(aux_part, 0, 64*NEXP*sizeof(float), stream);

  k_router<<<N_TOK/4, 256, 0, stream>>>(x, gate_w, topidx, topw, aux_part);
  k_scan<<<1, 1024, 0, stream>>>(topidx, aux_part, slot_token, tok_slots,
                                 out + (size_t)N_TOK*DIM);
  k_tcv_all<<<dim3(32, 16, 24), 256, 0, stream>>>(w_gate, w_up, w_down, B1, wdT);
  k_gather<<<NSLOT, 256, 0, stream>>>(x, slot_token, disp);
  k_gemm8<DIM, DIM, 1><<<1280, 512, 0, stream>>>(disp, B1, hidden, nullptr);
  k_gemm8<DIM, FF, 2><<<640, 512, 0, stream>>>(hidden, wdT, P0, P1);
  k_combine<<<N_TOK/2, 256, 0, stream>>>(P0, P1, tok_slots, topw, out);
}

// Round 12
// 471.815 us; speedup vs baseline: 1.1295x; 1.1295x over previous
//
#include <hip/hip_runtime.h>
#include <stdint.h>

#define N_TOK 16384
#define DIM   1024
#define NEXP  8
#define FF    2048
#define CAP   2560
#define NSLOT (NEXP*CAP)   // 20480

using f32x4  = __attribute__((ext_vector_type(4))) float;
using bf16x8 = __attribute__((ext_vector_type(8))) short;

__device__ __forceinline__ unsigned short f2bf(float f){
  union { float f; unsigned u; } c; c.f = f;
  unsigned u = c.u + 0x7FFFu + ((c.u >> 16) & 1u);   // RNE
  return (unsigned short)(u >> 16);
}
__device__ __forceinline__ float bf2f(unsigned short h){
  union { unsigned u; float f; } c; c.u = ((unsigned)h) << 16; return c.f;
}

__device__ __forceinline__ void gld16(const unsigned short* g, unsigned short* l){
  __builtin_amdgcn_global_load_lds((__attribute__((address_space(1))) void*)(void*)g,
                                   (__attribute__((address_space(3))) void*)l,
                                   16, 0, 0);
}

#define HBAR __builtin_amdgcn_s_barrier()
#define LG0  asm volatile("s_waitcnt lgkmcnt(0)" ::: "memory")

// ---------------- router: fp64 logits/softmax; per-wave aux partial stores ----------------
__global__ __launch_bounds__(256) void k_router(
    const float* __restrict__ x, const float* __restrict__ gate_w,
    int* __restrict__ topidx, float* __restrict__ topw,
    float* __restrict__ wavepart)            // [N_TOK][8] per-token probs
{
  __shared__ float gwT[NEXP][DIM];
  int tid = threadIdx.x;
  for (int i = tid; i < DIM*NEXP; i += 256) gwT[i & 7][i >> 3] = gate_w[i];
  __syncthreads();
  int wave = tid >> 6, lane = tid & 63;
  int t = blockIdx.x * 4 + wave;
  const float* xr = x + (size_t)t * DIM;
  double acc[NEXP];
  #pragma unroll
  for (int e = 0; e < NEXP; e++) acc[e] = 0.0;
  for (int j = 0; j < DIM/64; j++){
    double xv = (double)xr[lane + 64*j];
    #pragma unroll
    for (int e = 0; e < NEXP; e++) acc[e] += xv * (double)gwT[e][lane + 64*j];
  }
  #pragma unroll
  for (int off = 32; off >= 1; off >>= 1){
    #pragma unroll
    for (int e = 0; e < NEXP; e++) acc[e] += __shfl_xor(acc[e], off, 64);
  }
  if (lane == 0){
    double m = acc[0];
    #pragma unroll
    for (int e = 1; e < NEXP; e++) m = fmax(m, acc[e]);
    double p[NEXP], Z = 0.0;
    #pragma unroll
    for (int e = 0; e < NEXP; e++){ p[e] = exp(acc[e] - m); Z += p[e]; }
    double invZ = 1.0 / Z;
    #pragma unroll
    for (int e = 0; e < NEXP; e++) p[e] *= invZ;
    float4* wp = (float4*)(wavepart + (size_t)t*NEXP);
    wp[0] = make_float4((float)p[0], (float)p[1], (float)p[2], (float)p[3]);
    wp[1] = make_float4((float)p[4], (float)p[5], (float)p[6], (float)p[7]);
    int i0 = 0; double p0 = p[0];
    #pragma unroll
    for (int e = 1; e < NEXP; e++) if (p[e] > p0){ p0 = p[e]; i0 = e; }
    int i1 = (i0 == 0) ? 1 : 0; double p1 = p[i1];
    #pragma unroll
    for (int e = 0; e < NEXP; e++) if (e != i0 && p[e] > p1){ p1 = p[e]; i1 = e; }
    double s = p0 + p1;
    topidx[t*2+0] = i0; topidx[t*2+1] = i1;
    topw [t*2+0] = (float)(p0/s); topw[t*2+1] = (float)(p1/s);
  }
}

// ---------------- ordered capacity scan + aux from per-wave partials ----------------
__global__ __launch_bounds__(1024) void k_scan(
    const int* __restrict__ topidx, const float* __restrict__ wavepart,
    int* __restrict__ slot_token, int* __restrict__ tok_slots,
    float* __restrict__ aux_out)
{
  __shared__ int sc[1024][NEXP];
  const int t = threadIdx.x;
  const int base_i = t * 32;
  int ids[32];
  #pragma unroll
  for (int j = 0; j < 32; j++) ids[j] = topidx[base_i + j];
  int b[NEXP];
  #pragma unroll
  for (int e = 0; e < NEXP; e++) b[e] = 0;
  #pragma unroll
  for (int j = 0; j < 32; j++){
    #pragma unroll
    for (int e = 0; e < NEXP; e++) if (ids[j] == e) b[e]++;
  }
  #pragma unroll
  for (int e = 0; e < NEXP; e++) sc[t][e] = b[e];
  __syncthreads();
  for (int off = 1; off < 1024; off <<= 1){
    int tmp[NEXP];
    #pragma unroll
    for (int e = 0; e < NEXP; e++) tmp[e] = (t >= off) ? sc[t-off][e] : 0;
    __syncthreads();
    #pragma unroll
    for (int e = 0; e < NEXP; e++) sc[t][e] += tmp[e];
    __syncthreads();
  }
  int myb[NEXP];
  #pragma unroll
  for (int e = 0; e < NEXP; e++) myb[e] = sc[t][e] - b[e];
  int cnt[NEXP];
  #pragma unroll
  for (int e = 0; e < NEXP; e++) cnt[e] = sc[1023][e];
  #pragma unroll
  for (int j = 0; j < 32; j++){
    int slot = -1;
    #pragma unroll
    for (int e = 0; e < NEXP; e++){
      if (ids[j] == e){
        int r = myb[e]; myb[e] = r + 1;
        if (r < CAP){
          slot = e*CAP + r;
          slot_token[slot] = (base_i + j) >> 1;
        }
      }
    }
    tok_slots[base_i + j] = slot;
  }
  // ---- aux: reduce per-token probs partials (512 KB, block-wide) ----
  __syncthreads();
  float pe[NEXP];
  #pragma unroll
  for (int e = 0; e < NEXP; e++) pe[e] = 0.f;
  for (int i = t; i < N_TOK; i += 1024){
    const float4* pr = (const float4*)(wavepart + (size_t)i*NEXP);
    float4 v0 = pr[0], v1 = pr[1];
    pe[0] += v0.x; pe[1] += v0.y; pe[2] += v0.z; pe[3] += v0.w;
    pe[4] += v1.x; pe[5] += v1.y; pe[6] += v1.z; pe[7] += v1.w;
  }
  #pragma unroll
  for (int off = 32; off >= 1; off >>= 1){
    #pragma unroll
    for (int e = 0; e < NEXP; e++) pe[e] += __shfl_xor(pe[e], off, 64);
  }
  __syncthreads();
  float* scf = (float*)&sc[0][0];
  const int wv = t >> 6, ln = t & 63;
  if (ln == 0){
    #pragma unroll
    for (int e = 0; e < NEXP; e++) scf[wv*NEXP + e] = pe[e];
  }
  __syncthreads();
  if (t == 0){
    float aux = 0.f;
    #pragma unroll
    for (int e = 0; e < NEXP; e++){
      float P = 0.f;
      for (int w = 0; w < 16; w++) P += scf[w*NEXP + e];
      P /= (float)N_TOK;
      float f = (float)cnt[e] / ((float)(N_TOK*2) + 1e-9f);
      aux += f * P;
    }
    aux_out[0] = (float)NEXP * aux * 0.01f;
  }
}

// ---------------- merged transpose+cast: all three weights in one launch ----------------
__global__ __launch_bounds__(256) void k_tcv_all(
    const float* __restrict__ wg, const float* __restrict__ wu, const float* __restrict__ wd,
    unsigned short* __restrict__ B1, unsigned short* __restrict__ wdT)
{
  __shared__ float tt[64][65];
  const int z = blockIdx.z, mode = z >> 3, e = z & 7;
  const float* in; unsigned short* out; int R, C, ct, rt;
  if (mode < 2){
    in  = (mode == 0 ? wg : wu) + (size_t)e * DIM * FF;
    out = B1 + (size_t)e * 2 * FF * DIM;
    R = DIM; C = FF; ct = blockIdx.x; rt = blockIdx.y;      // 32 x 16
  } else {
    in  = wd + (size_t)e * FF * DIM;
    out = wdT + (size_t)e * DIM * FF;
    R = FF; C = DIM; ct = blockIdx.y; rt = blockIdx.x;      // 16 x 32
  }
  const int c0 = ct * 64, r0 = rt * 64;
  const int tid = threadIdx.x;
  #pragma unroll
  for (int i = 0; i < 4; i++){
    int idx = i*256 + tid;
    int row = idx >> 4, c4 = idx & 15;
    float4 v = *(const float4*)(in + (size_t)(r0 + row)*C + c0 + c4*4);
    tt[c4*4+0][row] = v.x; tt[c4*4+1][row] = v.y;
    tt[c4*4+2][row] = v.z; tt[c4*4+3][row] = v.w;
  }
  __syncthreads();
  #pragma unroll
  for (int i = 0; i < 2; i++){
    int cl = i*32 + (tid >> 3);
    int rs = (tid & 7) * 8;
    int c  = c0 + cl;
    int orow = (mode == 0) ? ((c>>4)*32 + (c&15))
             : (mode == 1) ? ((c>>4)*32 + 16 + (c&15))
             : c;
    unsigned long long pk0 = 0, pk1 = 0;
    #pragma unroll
    for (int j = 0; j < 4; j++) pk0 |= (unsigned long long)f2bf(tt[cl][rs+j]) << (16*j);
    #pragma unroll
    for (int j = 0; j < 4; j++) pk1 |= (unsigned long long)f2bf(tt[cl][rs+4+j]) << (16*j);
    unsigned long long* dst = (unsigned long long*)(out + (size_t)orow*R + r0 + rs);
    dst[0] = pk0; dst[1] = pk1;
  }
}

// ---------------- gather x rows into dispatched bf16 ----------------
__global__ __launch_bounds__(256) void k_gather(
    const float* __restrict__ x, const int* __restrict__ slot_token,
    unsigned short* __restrict__ disp)
{
  const int s = blockIdx.x;
  const int t = slot_token[s];
  const int tid = threadIdx.x;
  unsigned long long pk = 0ull;
  if (t >= 0){
    float4 v = *(const float4*)(x + (size_t)t*DIM + tid*4);
    pk =  (unsigned long long)f2bf(v.x)
       | ((unsigned long long)f2bf(v.y) << 16)
       | ((unsigned long long)f2bf(v.z) << 32)
       | ((unsigned long long)f2bf(v.w) << 48);
  }
  *(unsigned long long*)(disp + (size_t)s*DIM + tid*4) = pk;
}

// ================= ring-4 half-K 256x256 GEMM core (R8-proven schedule) =================
__device__ __forceinline__ void stg(const unsigned short* gsrc, int ldg,
                                    unsigned short* Lh, int wave, int lane){
  const int sl = (lane & 3) ^ ((lane >> 3) & 3);   // inverse-swizzled source slot
  #pragma unroll
  for (int j = 0; j < 2; j++){
    int bi = wave*2 + j;
    gld16(gsrc + (size_t)(bi*16 + (lane >> 2))*ldg + sl*8, Lh + bi*512);
  }
}
__device__ __forceinline__ bf16x8 frd(const unsigned short* Lh, int r, int g){
  return *(const bf16x8*)(Lh + r*32 + (((g ^ ((r >> 1) & 3))) << 3));
}
template<int MG>
__device__ __forceinline__ void mm16(f32x4 (&acc)[8][4], const bf16x8 (&a)[4], const bf16x8 (&b)[4]){
  #pragma unroll
  for (int i = 0; i < 4; i++)
    #pragma unroll
    for (int n = 0; n < 4; n++)
      acc[MG*4+i][n] = __builtin_amdgcn_mfma_f32_16x16x32_bf16(a[i], b[n], acc[MG*4+i][n], 0, 0, 0);
}

#define HALF_STEP(RS, DOSTG, VMW, ASRC, BSRC)                                   \
  {                                                                             \
    unsigned short* LA = lds + (RS)*16384;                                      \
    unsigned short* LB = LA + 8192;                                             \
    unsigned short* NS = lds + (((RS)+3)&3)*16384;                              \
    bf16x8 a[4], b[4];                                                          \
    _Pragma("unroll")                                                           \
    for (int i = 0; i < 4; i++) a[i] = frd(LA, wr*128 + i*16 + l15, g);         \
    _Pragma("unroll")                                                           \
    for (int n = 0; n < 4; n++) b[n] = frd(LB, wc*64 + n*16 + l15, g);          \
    if (DOSTG) stg(ASRC, LDG, NS, wave, lane);                                  \
    HBAR; LG0;                                                                  \
    __builtin_amdgcn_s_setprio(1);  mm16<0>(acc, a, b);                         \
    __builtin_amdgcn_s_setprio(0);                                              \
    HBAR;                                                                       \
    _Pragma("unroll")                                                           \
    for (int i = 0; i < 4; i++) a[i] = frd(LA, wr*128 + (4+i)*16 + l15, g);     \
    if (DOSTG) stg(BSRC, LDG, NS + 8192, wave, lane);                           \
    HBAR; LG0;                                                                  \
    __builtin_amdgcn_s_setprio(1);  mm16<1>(acc, a, b);                         \
    __builtin_amdgcn_s_setprio(0);                                              \
    if ((VMW) == 4) { asm volatile("s_waitcnt vmcnt(4)" ::: "memory"); }        \
    else if ((VMW) == 0) { asm volatile("s_waitcnt vmcnt(0)" ::: "memory"); }   \
    HBAR;                                                                       \
  }

// EPI 1: gemm1 (silu fused -> hidden). EPI 2: gemm2 K-split -> bf16 partial ks.
template<int KDIM, int LDG, int EPI>
__global__ __launch_bounds__(512, 2) void k_gemm8(
    const unsigned short* __restrict__ A,
    const unsigned short* __restrict__ B,
    unsigned short* __restrict__ Out0,
    unsigned short* __restrict__ Out1)
{
  constexpr int NH    = KDIM / 32;               // 32 halves
  constexpr int BROWS = (EPI == 1) ? 2*FF : DIM;
  constexpr int LDO   = (EPI == 1) ? FF : DIM;
  __shared__ unsigned short lds[65536];          // 128 KiB = 4 half-slots
  const int id = blockIdx.x;
  const int e  = id & 7;                          // XCD-chunked: expert per XCD
  int t  = id >> 3;
  int ks = 0;
  if (EPI == 2){ ks = t & 1; t >>= 1; }           // K-slice
  const int mt = t % 10, nt = t / 10;
  const int m0 = mt*256, n0 = nt*256;
  const unsigned short* Ab = A + ((size_t)e*CAP   + m0) * LDG + (size_t)ks*KDIM;
  const unsigned short* Bb = B + ((size_t)e*BROWS + n0) * LDG + (size_t)ks*KDIM;
  const int tid = threadIdx.x, wave = tid >> 6, lane = tid & 63;
  const int wr = wave >> 2, wc = wave & 3;        // 2M x 4N waves
  const int g = lane >> 4, l15 = lane & 15;

  f32x4 acc[8][4];
  const f32x4 z4 = {0.f,0.f,0.f,0.f};
  #pragma unroll
  for (int i = 0; i < 8; i++)
    #pragma unroll
    for (int n = 0; n < 4; n++) acc[i][n] = z4;

  stg(Ab,      LDG, lds + 0*16384,        wave, lane);
  stg(Bb,      LDG, lds + 0*16384 + 8192, wave, lane);
  stg(Ab + 32, LDG, lds + 1*16384,        wave, lane);
  stg(Bb + 32, LDG, lds + 1*16384 + 8192, wave, lane);
  stg(Ab + 64, LDG, lds + 2*16384,        wave, lane);
  stg(Bb + 64, LDG, lds + 2*16384 + 8192, wave, lane);
  asm volatile("s_waitcnt vmcnt(4)" ::: "memory");
  HBAR;

  for (int h = 0; h + 8 <= NH; h += 4){
    HALF_STEP(0, true, -1, Ab + (size_t)(h+3)*32, Bb + (size_t)(h+3)*32);
    HALF_STEP(1, true,  4, Ab + (size_t)(h+4)*32, Bb + (size_t)(h+4)*32);
    HALF_STEP(2, true, -1, Ab + (size_t)(h+5)*32, Bb + (size_t)(h+5)*32);
    HALF_STEP(3, true,  4, Ab + (size_t)(h+6)*32, Bb + (size_t)(h+6)*32);
  }
  HALF_STEP(0, true, -1, Ab + (size_t)(NH-1)*32, Bb + (size_t)(NH-1)*32);
  HALF_STEP(1, false, 0, Ab, Bb);
  HALF_STEP(2, false, -1, Ab, Bb);
  HALF_STEP(3, false, -1, Ab, Bb);

  if (EPI == 1){
    unsigned short* H = Out0 + ((size_t)e*CAP + m0 + wr*128) * (size_t)LDO;
    const int hc0 = (n0 + wc*64) >> 1;
    #pragma unroll
    for (int mf = 0; mf < 8; mf++)
      #pragma unroll
      for (int q = 0; q < 4; q++){
        int r = mf*16 + g*4 + q;
        #pragma unroll
        for (int p = 0; p < 2; p++){
          float gg = acc[mf][2*p][q], uu = acc[mf][2*p+1][q];
          float h = gg / (1.f + __expf(-gg)) * uu;
          H[(size_t)r*LDO + hc0 + p*16 + l15] = f2bf(h);
        }
      }
  } else {
    unsigned short* P = (ks ? Out1 : Out0);
    unsigned short* O = P + ((size_t)e*CAP + m0 + wr*128) * (size_t)LDO + n0 + wc*64;
    #pragma unroll
    for (int mf = 0; mf < 8; mf++)
      #pragma unroll
      for (int q = 0; q < 4; q++){
        int r = mf*16 + g*4 + q;
        #pragma unroll
        for (int n = 0; n < 4; n++)
          O[(size_t)r*LDO + n*16 + l15] = f2bf(acc[mf][n][q]);
      }
  }
}

// ---------------- combine: out[t] = sum_k w_k * (P0[slot_k] + P1[slot_k]) ----------------
__global__ __launch_bounds__(256) void k_combine(
    const unsigned short* __restrict__ P0, const unsigned short* __restrict__ P1,
    const int* __restrict__ tok_slots, const float* __restrict__ topw,
    float* __restrict__ out)
{
  const int t = blockIdx.x*2 + (threadIdx.x >> 7);
  const int tid = threadIdx.x & 127;
  const int s0 = tok_slots[t*2+0], s1 = tok_slots[t*2+1];
  const float w0 = topw[t*2+0], w1 = topw[t*2+1];
  float r[8];
  #pragma unroll
  for (int j = 0; j < 8; j++) r[j] = 0.f;
  if (s0 >= 0){
    bf16x8 v0 = *(const bf16x8*)(P0 + (size_t)s0*DIM + tid*8);
    bf16x8 v1 = *(const bf16x8*)(P1 + (size_t)s0*DIM + tid*8);
    #pragma unroll
    for (int j = 0; j < 8; j++)
      r[j] += w0 * (bf2f((unsigned short)v0[j]) + bf2f((unsigned short)v1[j]));
  }
  if (s1 >= 0){
    bf16x8 v0 = *(const bf16x8*)(P0 + (size_t)s1*DIM + tid*8);
    bf16x8 v1 = *(const bf16x8*)(P1 + (size_t)s1*DIM + tid*8);
    #pragma unroll
    for (int j = 0; j < 8; j++)
      r[j] += w1 * (bf2f((unsigned short)v0[j]) + bf2f((unsigned short)v1[j]));
  }
  float4* o = (float4*)(out + (size_t)t*DIM + tid*8);
  o[0] = make_float4(r[0], r[1], r[2], r[3]);
  o[1] = make_float4(r[4], r[5], r[6], r[7]);
}

extern "C" void kernel_launch(void* const* d_in, const int* in_sizes, int n_in,
                              void* d_out, int out_size, void* d_ws, size_t ws_size,
                              hipStream_t stream)
{
  const float* x      = (const float*)d_in[0];
  const float* gate_w = (const float*)d_in[1];
  const float* w_gate = (const float*)d_in[2];
  const float* w_up   = (const float*)d_in[3];
  const float* w_down = (const float*)d_in[4];
  float* out = (float*)d_out;

  uint8_t* ws = (uint8_t*)d_ws;
  int*   topidx       = (int*)ws;               ws += (size_t)N_TOK*2*4;
  float* topw         = (float*)ws;             ws += (size_t)N_TOK*2*4;
  int*   slot_token   = (int*)ws;               ws += (size_t)NSLOT*4;
  int*   tok_slots    = (int*)ws;               ws += (size_t)N_TOK*2*4;
  float* wavepart     = (float*)ws;             ws += (size_t)N_TOK*NEXP*4;
  unsigned short* disp   = (unsigned short*)ws; ws += (size_t)NSLOT*DIM*2;     // P0 aliases after gemm1
  unsigned short* hidden = (unsigned short*)ws; ws += (size_t)NSLOT*FF*2;
  unsigned short* B1     = (unsigned short*)ws; ws += (size_t)NEXP*2*FF*DIM*2; // P1 aliases after gemm1
  unsigned short* wdT    = (unsigned short*)ws; ws += (size_t)NEXP*DIM*FF*2;
  size_t need = (size_t)(ws - (uint8_t*)d_ws);
  if (ws_size < need) return;
  unsigned short* P0 = disp;   // dead after gemm1 consumes it
  unsigned short* P1 = B1;     // dead after gemm1 consumes it (67 MB >= 42 MB)

  hipMemsetAsync(slot_token, 0xFF, (size_t)NSLOT * sizeof(int), stream);

  k_router<<<N_TOK/4, 256, 0, stream>>>(x, gate_w, topidx, topw, wavepart);
  k_scan<<<1, 1024, 0, stream>>>(topidx, wavepart, slot_token, tok_slots,
                                 out + (size_t)N_TOK*DIM);
  k_tcv_all<<<dim3(32, 16, 24), 256, 0, stream>>>(w_gate, w_up, w_down, B1, wdT);
  k_gather<<<NSLOT, 256, 0, stream>>>(x, slot_token, disp);
  k_gemm8<DIM, DIM, 1><<<1280, 512, 0, stream>>>(disp, B1, hidden, nullptr);
  k_gemm8<DIM, FF, 2><<<640, 512, 0, stream>>>(hidden, wdT, P0, P1);
  k_combine<<<N_TOK/2, 256, 0, stream>>>(P0, P1, tok_slots, topw, out);
}

// Round 13
// 440.811 us; speedup vs baseline: 1.2089x; 1.0703x over previous
//
#include <hip/hip_runtime.h>
#include <stdint.h>

#define N_TOK 16384
#define DIM   1024
#define NEXP  8
#define FF    2048
#define CAP   2560
#define NSLOT (NEXP*CAP)   // 20480

using f32x4  = __attribute__((ext_vector_type(4))) float;
using bf16x8 = __attribute__((ext_vector_type(8))) short;

__device__ __forceinline__ unsigned short f2bf(float f){
  union { float f; unsigned u; } c; c.f = f;
  unsigned u = c.u + 0x7FFFu + ((c.u >> 16) & 1u);   // RNE
  return (unsigned short)(u >> 16);
}
__device__ __forceinline__ float bf2f(unsigned short h){
  union { unsigned u; float f; } c; c.u = ((unsigned)h) << 16; return c.f;
}

__device__ __forceinline__ void gld16(const unsigned short* g, unsigned short* l){
  __builtin_amdgcn_global_load_lds((__attribute__((address_space(1))) void*)(void*)g,
                                   (__attribute__((address_space(3))) void*)l,
                                   16, 0, 0);
}

#define HBAR __builtin_amdgcn_s_barrier()
#define LG0  asm volatile("s_waitcnt lgkmcnt(0)" ::: "memory")

// ---------------- router: fp64 logits/softmax; per-token aux partial stores ----------------
__global__ __launch_bounds__(256) void k_router(
    const float* __restrict__ x, const float* __restrict__ gate_w,
    int* __restrict__ topidx, float* __restrict__ topw,
    float* __restrict__ wavepart)            // [N_TOK][8] per-token probs
{
  __shared__ float gwT[NEXP][DIM];
  int tid = threadIdx.x;
  for (int i = tid; i < DIM*NEXP; i += 256) gwT[i & 7][i >> 3] = gate_w[i];
  __syncthreads();
  int wave = tid >> 6, lane = tid & 63;
  int t = blockIdx.x * 4 + wave;
  const float* xr = x + (size_t)t * DIM;
  double acc[NEXP];
  #pragma unroll
  for (int e = 0; e < NEXP; e++) acc[e] = 0.0;
  for (int j = 0; j < DIM/64; j++){
    double xv = (double)xr[lane + 64*j];
    #pragma unroll
    for (int e = 0; e < NEXP; e++) acc[e] += xv * (double)gwT[e][lane + 64*j];
  }
  #pragma unroll
  for (int off = 32; off >= 1; off >>= 1){
    #pragma unroll
    for (int e = 0; e < NEXP; e++) acc[e] += __shfl_xor(acc[e], off, 64);
  }
  if (lane == 0){
    double m = acc[0];
    #pragma unroll
    for (int e = 1; e < NEXP; e++) m = fmax(m, acc[e]);
    double p[NEXP], Z = 0.0;
    #pragma unroll
    for (int e = 0; e < NEXP; e++){ p[e] = exp(acc[e] - m); Z += p[e]; }
    double invZ = 1.0 / Z;
    #pragma unroll
    for (int e = 0; e < NEXP; e++) p[e] *= invZ;
    float4* wp = (float4*)(wavepart + (size_t)t*NEXP);
    wp[0] = make_float4((float)p[0], (float)p[1], (float)p[2], (float)p[3]);
    wp[1] = make_float4((float)p[4], (float)p[5], (float)p[6], (float)p[7]);
    int i0 = 0; double p0 = p[0];
    #pragma unroll
    for (int e = 1; e < NEXP; e++) if (p[e] > p0){ p0 = p[e]; i0 = e; }
    int i1 = (i0 == 0) ? 1 : 0; double p1 = p[i1];
    #pragma unroll
    for (int e = 0; e < NEXP; e++) if (e != i0 && p[e] > p1){ p1 = p[e]; i1 = e; }
    double s = p0 + p1;
    topidx[t*2+0] = i0; topidx[t*2+1] = i1;
    topw [t*2+0] = (float)(p0/s); topw[t*2+1] = (float)(p1/s);
  }
}

// ---------------- fused: block 0 = ordered scan + aux; blocks 1.. = transpose+cast ----------------
// tcv tiles: bid-1 = z*512 + rt*32 + ct; z = mode*8+e.
__global__ __launch_bounds__(1024) void k_scan_tcv(
    const int* __restrict__ topidx, const float* __restrict__ wavepart,
    int* __restrict__ slot_token, int* __restrict__ tok_slots,
    float* __restrict__ aux_out,
    const float* __restrict__ wg, const float* __restrict__ wu, const float* __restrict__ wd,
    unsigned short* __restrict__ B1, unsigned short* __restrict__ wdT)
{
  __shared__ uint8_t smem[32768];
  const int t = threadIdx.x;

  if (blockIdx.x == 0){
    // ======== scan (proven R12 algorithm, verbatim) ========
    int (*sc)[NEXP] = (int(*)[NEXP])smem;    // [1024][8] = 32 KB
    const int base_i = t * 32;
    int ids[32];
    #pragma unroll
    for (int j = 0; j < 32; j++) ids[j] = topidx[base_i + j];
    int b[NEXP];
    #pragma unroll
    for (int e = 0; e < NEXP; e++) b[e] = 0;
    #pragma unroll
    for (int j = 0; j < 32; j++){
      #pragma unroll
      for (int e = 0; e < NEXP; e++) if (ids[j] == e) b[e]++;
    }
    #pragma unroll
    for (int e = 0; e < NEXP; e++) sc[t][e] = b[e];
    __syncthreads();
    for (int off = 1; off < 1024; off <<= 1){
      int tmp[NEXP];
      #pragma unroll
      for (int e = 0; e < NEXP; e++) tmp[e] = (t >= off) ? sc[t-off][e] : 0;
      __syncthreads();
      #pragma unroll
      for (int e = 0; e < NEXP; e++) sc[t][e] += tmp[e];
      __syncthreads();
    }
    int myb[NEXP];
    #pragma unroll
    for (int e = 0; e < NEXP; e++) myb[e] = sc[t][e] - b[e];
    int cnt[NEXP];
    #pragma unroll
    for (int e = 0; e < NEXP; e++) cnt[e] = sc[1023][e];
    #pragma unroll
    for (int j = 0; j < 32; j++){
      int slot = -1;
      #pragma unroll
      for (int e = 0; e < NEXP; e++){
        if (ids[j] == e){
          int r = myb[e]; myb[e] = r + 1;
          if (r < CAP){
            slot = e*CAP + r;
            slot_token[slot] = (base_i + j) >> 1;
          }
        }
      }
      tok_slots[base_i + j] = slot;
    }
    // ---- aux: reduce per-token probs partials ----
    __syncthreads();
    float pe[NEXP];
    #pragma unroll
    for (int e = 0; e < NEXP; e++) pe[e] = 0.f;
    for (int i = t; i < N_TOK; i += 1024){
      const float4* pr = (const float4*)(wavepart + (size_t)i*NEXP);
      float4 v0 = pr[0], v1 = pr[1];
      pe[0] += v0.x; pe[1] += v0.y; pe[2] += v0.z; pe[3] += v0.w;
      pe[4] += v1.x; pe[5] += v1.y; pe[6] += v1.z; pe[7] += v1.w;
    }
    #pragma unroll
    for (int off = 32; off >= 1; off >>= 1){
      #pragma unroll
      for (int e = 0; e < NEXP; e++) pe[e] += __shfl_xor(pe[e], off, 64);
    }
    __syncthreads();
    float* scf = (float*)smem;
    const int wv = t >> 6, ln = t & 63;
    if (ln == 0){
      #pragma unroll
      for (int e = 0; e < NEXP; e++) scf[wv*NEXP + e] = pe[e];
    }
    __syncthreads();
    if (t == 0){
      float aux = 0.f;
      #pragma unroll
      for (int e = 0; e < NEXP; e++){
        float P = 0.f;
        for (int w = 0; w < 16; w++) P += scf[w*NEXP + e];
        P /= (float)N_TOK;
        float f = (float)cnt[e] / ((float)(N_TOK*2) + 1e-9f);
        aux += f * P;
      }
      aux_out[0] = (float)NEXP * aux * 0.01f;
    }
  } else {
    // ======== transpose+cast tile, 1024 threads: 1 float4 load + 1 u64 store ========
    float (*tt)[65] = (float(*)[65])smem;    // [64][65] = 16.6 KB
    const int bid = blockIdx.x - 1;
    const int z = bid >> 9, rem = bid & 511;
    const int mode = z >> 3, e = z & 7;
    const float* in; unsigned short* out; int R, C, ct, rt;
    if (mode < 2){
      in  = (mode == 0 ? wg : wu) + (size_t)e * DIM * FF;
      out = B1 + (size_t)e * 2 * FF * DIM;
      R = DIM; C = FF; ct = rem & 31; rt = rem >> 5;       // 32 ct x 16 rt
    } else {
      in  = wd + (size_t)e * FF * DIM;
      out = wdT + (size_t)e * DIM * FF;
      R = FF; C = DIM; ct = rem >> 5; rt = rem & 31;      // 16 ct x 32 rt
    }
    const int c0 = ct * 64, r0 = rt * 64;
    {
      int row = t >> 4, c4 = t & 15;
      float4 v = *(const float4*)(in + (size_t)(r0 + row)*C + c0 + c4*4);
      tt[c4*4+0][row] = v.x; tt[c4*4+1][row] = v.y;
      tt[c4*4+2][row] = v.z; tt[c4*4+3][row] = v.w;
    }
    __syncthreads();
    {
      int cl = t >> 4;                   // 0..63 local col
      int rs = (t & 15) * 4;             // 4 consecutive rows
      int c  = c0 + cl;
      int orow = (mode == 0) ? ((c>>4)*32 + (c&15))
               : (mode == 1) ? ((c>>4)*32 + 16 + (c&15))
               : c;
      unsigned long long pk = 0;
      #pragma unroll
      for (int j = 0; j < 4; j++) pk |= (unsigned long long)f2bf(tt[cl][rs+j]) << (16*j);
      *(unsigned long long*)(out + (size_t)orow*R + r0 + rs) = pk;
    }
  }
}

// ---------------- gather x rows into dispatched bf16 ----------------
__global__ __launch_bounds__(256) void k_gather(
    const float* __restrict__ x, const int* __restrict__ slot_token,
    unsigned short* __restrict__ disp)
{
  const int s = blockIdx.x;
  const int t = slot_token[s];
  const int tid = threadIdx.x;
  unsigned long long pk = 0ull;
  if (t >= 0){
    float4 v = *(const float4*)(x + (size_t)t*DIM + tid*4);
    pk =  (unsigned long long)f2bf(v.x)
       | ((unsigned long long)f2bf(v.y) << 16)
       | ((unsigned long long)f2bf(v.z) << 32)
       | ((unsigned long long)f2bf(v.w) << 48);
  }
  *(unsigned long long*)(disp + (size_t)s*DIM + tid*4) = pk;
}

// ================= ring-4 half-K 256x256 GEMM core (R8-proven schedule, FROZEN) =================
__device__ __forceinline__ void stg(const unsigned short* gsrc, int ldg,
                                    unsigned short* Lh, int wave, int lane){
  const int sl = (lane & 3) ^ ((lane >> 3) & 3);   // inverse-swizzled source slot
  #pragma unroll
  for (int j = 0; j < 2; j++){
    int bi = wave*2 + j;
    gld16(gsrc + (size_t)(bi*16 + (lane >> 2))*ldg + sl*8, Lh + bi*512);
  }
}
__device__ __forceinline__ bf16x8 frd(const unsigned short* Lh, int r, int g){
  return *(const bf16x8*)(Lh + r*32 + (((g ^ ((r >> 1) & 3))) << 3));
}
template<int MG>
__device__ __forceinline__ void mm16(f32x4 (&acc)[8][4], const bf16x8 (&a)[4], const bf16x8 (&b)[4]){
  #pragma unroll
  for (int i = 0; i < 4; i++)
    #pragma unroll
    for (int n = 0; n < 4; n++)
      acc[MG*4+i][n] = __builtin_amdgcn_mfma_f32_16x16x32_bf16(a[i], b[n], acc[MG*4+i][n], 0, 0, 0);
}

#define HALF_STEP(RS, DOSTG, VMW, ASRC, BSRC)                                   \
  {                                                                             \
    unsigned short* LA = lds + (RS)*16384;                                      \
    unsigned short* LB = LA + 8192;                                             \
    unsigned short* NS = lds + (((RS)+3)&3)*16384;                              \
    bf16x8 a[4], b[4];                                                          \
    _Pragma("unroll")                                                           \
    for (int i = 0; i < 4; i++) a[i] = frd(LA, wr*128 + i*16 + l15, g);         \
    _Pragma("unroll")                                                           \
    for (int n = 0; n < 4; n++) b[n] = frd(LB, wc*64 + n*16 + l15, g);          \
    if (DOSTG) stg(ASRC, LDG, NS, wave, lane);                                  \
    HBAR; LG0;                                                                  \
    __builtin_amdgcn_s_setprio(1);  mm16<0>(acc, a, b);                         \
    __builtin_amdgcn_s_setprio(0);                                              \
    HBAR;                                                                       \
    _Pragma("unroll")                                                           \
    for (int i = 0; i < 4; i++) a[i] = frd(LA, wr*128 + (4+i)*16 + l15, g);     \
    if (DOSTG) stg(BSRC, LDG, NS + 8192, wave, lane);                           \
    HBAR; LG0;                                                                  \
    __builtin_amdgcn_s_setprio(1);  mm16<1>(acc, a, b);                         \
    __builtin_amdgcn_s_setprio(0);                                              \
    if ((VMW) == 4) { asm volatile("s_waitcnt vmcnt(4)" ::: "memory"); }        \
    else if ((VMW) == 0) { asm volatile("s_waitcnt vmcnt(0)" ::: "memory"); }   \
    HBAR;                                                                       \
  }

// EPI 1: gemm1 (silu fused -> hidden). EPI 2: gemm2 K-split -> bf16 partial ks.
template<int KDIM, int LDG, int EPI>
__global__ __launch_bounds__(512, 2) void k_gemm8(
    const unsigned short* __restrict__ A,
    const unsigned short* __restrict__ B,
    unsigned short* __restrict__ Out0,
    unsigned short* __restrict__ Out1)
{
  constexpr int NH    = KDIM / 32;               // 32 halves
  constexpr int BROWS = (EPI == 1) ? 2*FF : DIM;
  constexpr int LDO   = (EPI == 1) ? FF : DIM;
  __shared__ unsigned short lds[65536];          // 128 KiB = 4 half-slots
  const int id = blockIdx.x;
  const int e  = id & 7;                          // XCD-chunked: expert per XCD
  int t  = id >> 3;
  int ks = 0;
  if (EPI == 2){ ks = t & 1; t >>= 1; }           // K-slice
  const int mt = t % 10, nt = t / 10;
  const int m0 = mt*256, n0 = nt*256;
  const unsigned short* Ab = A + ((size_t)e*CAP   + m0) * LDG + (size_t)ks*KDIM;
  const unsigned short* Bb = B + ((size_t)e*BROWS + n0) * LDG + (size_t)ks*KDIM;
  const int tid = threadIdx.x, wave = tid >> 6, lane = tid & 63;
  const int wr = wave >> 2, wc = wave & 3;        // 2M x 4N waves
  const int g = lane >> 4, l15 = lane & 15;

  f32x4 acc[8][4];
  const f32x4 z4 = {0.f,0.f,0.f,0.f};
  #pragma unroll
  for (int i = 0; i < 8; i++)
    #pragma unroll
    for (int n = 0; n < 4; n++) acc[i][n] = z4;

  stg(Ab,      LDG, lds + 0*16384,        wave, lane);
  stg(Bb,      LDG, lds + 0*16384 + 8192, wave, lane);
  stg(Ab + 32, LDG, lds + 1*16384,        wave, lane);
  stg(Bb + 32, LDG, lds + 1*16384 + 8192, wave, lane);
  stg(Ab + 64, LDG, lds + 2*16384,        wave, lane);
  stg(Bb + 64, LDG, lds + 2*16384 + 8192, wave, lane);
  asm volatile("s_waitcnt vmcnt(4)" ::: "memory");
  HBAR;

  for (int h = 0; h + 8 <= NH; h += 4){
    HALF_STEP(0, true, -1, Ab + (size_t)(h+3)*32, Bb + (size_t)(h+3)*32);
    HALF_STEP(1, true,  4, Ab + (size_t)(h+4)*32, Bb + (size_t)(h+4)*32);
    HALF_STEP(2, true, -1, Ab + (size_t)(h+5)*32, Bb + (size_t)(h+5)*32);
    HALF_STEP(3, true,  4, Ab + (size_t)(h+6)*32, Bb + (size_t)(h+6)*32);
  }
  HALF_STEP(0, true, -1, Ab + (size_t)(NH-1)*32, Bb + (size_t)(NH-1)*32);
  HALF_STEP(1, false, 0, Ab, Bb);
  HALF_STEP(2, false, -1, Ab, Bb);
  HALF_STEP(3, false, -1, Ab, Bb);

  if (EPI == 1){
    unsigned short* H = Out0 + ((size_t)e*CAP + m0 + wr*128) * (size_t)LDO;
    const int hc0 = (n0 + wc*64) >> 1;
    #pragma unroll
    for (int mf = 0; mf < 8; mf++)
      #pragma unroll
      for (int q = 0; q < 4; q++){
        int r = mf*16 + g*4 + q;
        #pragma unroll
        for (int p = 0; p < 2; p++){
          float gg = acc[mf][2*p][q], uu = acc[mf][2*p+1][q];
          float h = gg / (1.f + __expf(-gg)) * uu;
          H[(size_t)r*LDO + hc0 + p*16 + l15] = f2bf(h);
        }
      }
  } else {
    unsigned short* P = (ks ? Out1 : Out0);
    unsigned short* O = P + ((size_t)e*CAP + m0 + wr*128) * (size_t)LDO + n0 + wc*64;
    #pragma unroll
    for (int mf = 0; mf < 8; mf++)
      #pragma unroll
      for (int q = 0; q < 4; q++){
        int r = mf*16 + g*4 + q;
        #pragma unroll
        for (int n = 0; n < 4; n++)
          O[(size_t)r*LDO + n*16 + l15] = f2bf(acc[mf][n][q]);
      }
  }
}

// ---------------- combine: out[t] = sum_k w_k * (P0[slot_k] + P1[slot_k]) ----------------
__global__ __launch_bounds__(256) void k_combine(
    const unsigned short* __restrict__ P0, const unsigned short* __restrict__ P1,
    const int* __restrict__ tok_slots, const float* __restrict__ topw,
    float* __restrict__ out)
{
  const int t = blockIdx.x*2 + (threadIdx.x >> 7);
  const int tid = threadIdx.x & 127;
  const int s0 = tok_slots[t*2+0], s1 = tok_slots[t*2+1];
  const float w0 = topw[t*2+0], w1 = topw[t*2+1];
  float r[8];
  #pragma unroll
  for (int j = 0; j < 8; j++) r[j] = 0.f;
  if (s0 >= 0){
    bf16x8 v0 = *(const bf16x8*)(P0 + (size_t)s0*DIM + tid*8);
    bf16x8 v1 = *(const bf16x8*)(P1 + (size_t)s0*DIM + tid*8);
    #pragma unroll
    for (int j = 0; j < 8; j++)
      r[j] += w0 * (bf2f((unsigned short)v0[j]) + bf2f((unsigned short)v1[j]));
  }
  if (s1 >= 0){
    bf16x8 v0 = *(const bf16x8*)(P0 + (size_t)s1*DIM + tid*8);
    bf16x8 v1 = *(const bf16x8*)(P1 + (size_t)s1*DIM + tid*8);
    #pragma unroll
    for (int j = 0; j < 8; j++)
      r[j] += w1 * (bf2f((unsigned short)v0[j]) + bf2f((unsigned short)v1[j]));
  }
  float4* o = (float4*)(out + (size_t)t*DIM + tid*8);
  o[0] = make_float4(r[0], r[1], r[2], r[3]);
  o[1] = make_float4(r[4], r[5], r[6], r[7]);
}

extern "C" void kernel_launch(void* const* d_in, const int* in_sizes, int n_in,
                              void* d_out, int out_size, void* d_ws, size_t ws_size,
                              hipStream_t stream)
{
  const float* x      = (const float*)d_in[0];
  const float* gate_w = (const float*)d_in[1];
  const float* w_gate = (const float*)d_in[2];
  const float* w_up   = (const float*)d_in[3];
  const float* w_down = (const float*)d_in[4];
  float* out = (float*)d_out;

  uint8_t* ws = (uint8_t*)d_ws;
  int*   topidx       = (int*)ws;               ws += (size_t)N_TOK*2*4;
  float* topw         = (float*)ws;             ws += (size_t)N_TOK*2*4;
  int*   slot_token   = (int*)ws;               ws += (size_t)NSLOT*4;
  int*   tok_slots    = (int*)ws;               ws += (size_t)N_TOK*2*4;
  float* wavepart     = (float*)ws;             ws += (size_t)N_TOK*NEXP*4;
  unsigned short* disp   = (unsigned short*)ws; ws += (size_t)NSLOT*DIM*2;     // P0 aliases after gemm1
  unsigned short* hidden = (unsigned short*)ws; ws += (size_t)NSLOT*FF*2;
  unsigned short* B1     = (unsigned short*)ws; ws += (size_t)NEXP*2*FF*DIM*2; // P1 aliases after gemm1
  unsigned short* wdT    = (unsigned short*)ws; ws += (size_t)NEXP*DIM*FF*2;
  size_t need = (size_t)(ws - (uint8_t*)d_ws);
  if (ws_size < need) return;
  unsigned short* P0 = disp;   // dead after gemm1 consumes it
  unsigned short* P1 = B1;     // dead after gemm1 consumes it (67 MB >= 42 MB)

  hipMemsetAsync(slot_token, 0xFF, (size_t)NSLOT * sizeof(int), stream);

  k_router<<<N_TOK/4, 256, 0, stream>>>(x, gate_w, topidx, topw, wavepart);
  // fused: block 0 runs the ordered scan (+aux) while 12288 blocks do the weight transpose
  k_scan_tcv<<<12289, 1024, 0, stream>>>(topidx, wavepart, slot_token, tok_slots,
                                         out + (size_t)N_TOK*DIM,
                                         w_gate, w_up, w_down, B1, wdT);
  k_gather<<<NSLOT, 256, 0, stream>>>(x, slot_token, disp);
  k_gemm8<DIM, DIM, 1><<<1280, 512, 0, stream>>>(disp, B1, hidden, nullptr);
  k_gemm8<DIM, FF, 2><<<640, 512, 0, stream>>>(hidden, wdT, P0, P1);
  k_combine<<<N_TOK/2, 256, 0, stream>>>(P0, P1, tok_slots, topw, out);
}

// Round 14
// 435.922 us; speedup vs baseline: 1.2225x; 1.0112x over previous
//
#include <hip/hip_runtime.h>
#include <stdint.h>

#define N_TOK 16384
#define DIM   1024
#define NEXP  8
#define FF    2048
#define CAP   2560
#define NSLOT (NEXP*CAP)   // 20480

using f32x4  = __attribute__((ext_vector_type(4))) float;
using bf16x8 = __attribute__((ext_vector_type(8))) short;

__device__ __forceinline__ unsigned short f2bf(float f){
  union { float f; unsigned u; } c; c.f = f;
  unsigned u = c.u + 0x7FFFu + ((c.u >> 16) & 1u);   // RNE
  return (unsigned short)(u >> 16);
}
__device__ __forceinline__ float bf2f(unsigned short h){
  union { unsigned u; float f; } c; c.u = ((unsigned)h) << 16; return c.f;
}

__device__ __forceinline__ void gld16(const unsigned short* g, unsigned short* l){
  __builtin_amdgcn_global_load_lds((__attribute__((address_space(1))) void*)(void*)g,
                                   (__attribute__((address_space(3))) void*)l,
                                   16, 0, 0);
}

#define HBAR __builtin_amdgcn_s_barrier()
#define LG0  asm volatile("s_waitcnt lgkmcnt(0)" ::: "memory")

// ---------------- router: fp64 logits/softmax; per-token aux partial stores ----------------
__global__ __launch_bounds__(256) void k_router(
    const float* __restrict__ x, const float* __restrict__ gate_w,
    int* __restrict__ topidx, float* __restrict__ topw,
    float* __restrict__ wavepart)            // [N_TOK][8] per-token probs
{
  __shared__ float gwT[NEXP][DIM];
  int tid = threadIdx.x;
  for (int i = tid; i < DIM*NEXP; i += 256) gwT[i & 7][i >> 3] = gate_w[i];
  __syncthreads();
  int wave = tid >> 6, lane = tid & 63;
  int t = blockIdx.x * 4 + wave;
  const float* xr = x + (size_t)t * DIM;
  double acc[NEXP];
  #pragma unroll
  for (int e = 0; e < NEXP; e++) acc[e] = 0.0;
  for (int j = 0; j < DIM/64; j++){
    double xv = (double)xr[lane + 64*j];
    #pragma unroll
    for (int e = 0; e < NEXP; e++) acc[e] += xv * (double)gwT[e][lane + 64*j];
  }
  #pragma unroll
  for (int off = 32; off >= 1; off >>= 1){
    #pragma unroll
    for (int e = 0; e < NEXP; e++) acc[e] += __shfl_xor(acc[e], off, 64);
  }
  if (lane == 0){
    double m = acc[0];
    #pragma unroll
    for (int e = 1; e < NEXP; e++) m = fmax(m, acc[e]);
    double p[NEXP], Z = 0.0;
    #pragma unroll
    for (int e = 0; e < NEXP; e++){ p[e] = exp(acc[e] - m); Z += p[e]; }
    double invZ = 1.0 / Z;
    #pragma unroll
    for (int e = 0; e < NEXP; e++) p[e] *= invZ;
    float4* wp = (float4*)(wavepart + (size_t)t*NEXP);
    wp[0] = make_float4((float)p[0], (float)p[1], (float)p[2], (float)p[3]);
    wp[1] = make_float4((float)p[4], (float)p[5], (float)p[6], (float)p[7]);
    int i0 = 0; double p0 = p[0];
    #pragma unroll
    for (int e = 1; e < NEXP; e++) if (p[e] > p0){ p0 = p[e]; i0 = e; }
    int i1 = (i0 == 0) ? 1 : 0; double p1 = p[i1];
    #pragma unroll
    for (int e = 0; e < NEXP; e++) if (e != i0 && p[e] > p1){ p1 = p[e]; i1 = e; }
    double s = p0 + p1;
    topidx[t*2+0] = i0; topidx[t*2+1] = i1;
    topw [t*2+0] = (float)(p0/s); topw[t*2+1] = (float)(p1/s);
  }
}

// ---- fused: block 0 = ordered scan (+aux, +(-1) fill); blocks 1..12288 = transpose+cast;
//      blocks 12289..16384 = x fp32->bf16 cast ----
__global__ __launch_bounds__(1024) void k_scan_tcv(
    const int* __restrict__ topidx, const float* __restrict__ wavepart,
    int* __restrict__ slot_token, int* __restrict__ tok_slots,
    float* __restrict__ aux_out,
    const float* __restrict__ wg, const float* __restrict__ wu, const float* __restrict__ wd,
    unsigned short* __restrict__ B1, unsigned short* __restrict__ wdT,
    const float* __restrict__ x, unsigned short* __restrict__ xb)
{
  __shared__ uint8_t smem[32768];
  const int t = threadIdx.x;
  const int bidx = blockIdx.x;

  if (bidx == 0){
    // ======== scan (proven algorithm) ========
    int (*sc)[NEXP] = (int(*)[NEXP])smem;    // [1024][8] = 32 KB
    const int base_i = t * 32;
    int ids[32];
    #pragma unroll
    for (int j = 0; j < 32; j++) ids[j] = topidx[base_i + j];
    int b[NEXP];
    #pragma unroll
    for (int e = 0; e < NEXP; e++) b[e] = 0;
    #pragma unroll
    for (int j = 0; j < 32; j++){
      #pragma unroll
      for (int e = 0; e < NEXP; e++) if (ids[j] == e) b[e]++;
    }
    #pragma unroll
    for (int e = 0; e < NEXP; e++) sc[t][e] = b[e];
    __syncthreads();
    for (int off = 1; off < 1024; off <<= 1){
      int tmp[NEXP];
      #pragma unroll
      for (int e = 0; e < NEXP; e++) tmp[e] = (t >= off) ? sc[t-off][e] : 0;
      __syncthreads();
      #pragma unroll
      for (int e = 0; e < NEXP; e++) sc[t][e] += tmp[e];
      __syncthreads();
    }
    int myb[NEXP];
    #pragma unroll
    for (int e = 0; e < NEXP; e++) myb[e] = sc[t][e] - b[e];
    int cnt[NEXP];
    #pragma unroll
    for (int e = 0; e < NEXP; e++) cnt[e] = sc[1023][e];
    #pragma unroll
    for (int j = 0; j < 32; j++){
      int slot = -1;
      #pragma unroll
      for (int e = 0; e < NEXP; e++){
        if (ids[j] == e){
          int r = myb[e]; myb[e] = r + 1;
          if (r < CAP){
            slot = e*CAP + r;
            slot_token[slot] = (base_i + j) >> 1;
          }
        }
      }
      tok_slots[base_i + j] = slot;
    }
    // fill unfilled slots with -1 (replaces the memset launch)
    for (int idx = t; idx < NSLOT; idx += 1024){
      int e2 = idx / CAP, r2 = idx - e2*CAP;
      if (r2 >= cnt[e2]) slot_token[idx] = -1;
    }
    // ---- aux: reduce per-token probs partials ----
    __syncthreads();
    float pe[NEXP];
    #pragma unroll
    for (int e = 0; e < NEXP; e++) pe[e] = 0.f;
    for (int i = t; i < N_TOK; i += 1024){
      const float4* pr = (const float4*)(wavepart + (size_t)i*NEXP);
      float4 v0 = pr[0], v1 = pr[1];
      pe[0] += v0.x; pe[1] += v0.y; pe[2] += v0.z; pe[3] += v0.w;
      pe[4] += v1.x; pe[5] += v1.y; pe[6] += v1.z; pe[7] += v1.w;
    }
    #pragma unroll
    for (int off = 32; off >= 1; off >>= 1){
      #pragma unroll
      for (int e = 0; e < NEXP; e++) pe[e] += __shfl_xor(pe[e], off, 64);
    }
    __syncthreads();
    float* scf = (float*)smem;
    const int wv = t >> 6, ln = t & 63;
    if (ln == 0){
      #pragma unroll
      for (int e = 0; e < NEXP; e++) scf[wv*NEXP + e] = pe[e];
    }
    __syncthreads();
    if (t == 0){
      float aux = 0.f;
      #pragma unroll
      for (int e = 0; e < NEXP; e++){
        float P = 0.f;
        for (int w = 0; w < 16; w++) P += scf[w*NEXP + e];
        P /= (float)N_TOK;
        float f = (float)cnt[e] / ((float)(N_TOK*2) + 1e-9f);
        aux += f * P;
      }
      aux_out[0] = (float)NEXP * aux * 0.01f;
    }
  } else if (bidx <= 12288){
    // ======== transpose+cast tile ========
    float (*tt)[65] = (float(*)[65])smem;    // [64][65]
    const int bid = bidx - 1;
    const int z = bid >> 9, rem = bid & 511;
    const int mode = z >> 3, e = z & 7;
    const float* in; unsigned short* out; int R, C, ct, rt;
    if (mode < 2){
      in  = (mode == 0 ? wg : wu) + (size_t)e * DIM * FF;
      out = B1 + (size_t)e * 2 * FF * DIM;
      R = DIM; C = FF; ct = rem & 31; rt = rem >> 5;       // 32 ct x 16 rt
    } else {
      in  = wd + (size_t)e * FF * DIM;
      out = wdT + (size_t)e * DIM * FF;
      R = FF; C = DIM; ct = rem >> 5; rt = rem & 31;      // 16 ct x 32 rt
    }
    const int c0 = ct * 64, r0 = rt * 64;
    {
      int row = t >> 4, c4 = t & 15;
      float4 v = *(const float4*)(in + (size_t)(r0 + row)*C + c0 + c4*4);
      tt[c4*4+0][row] = v.x; tt[c4*4+1][row] = v.y;
      tt[c4*4+2][row] = v.z; tt[c4*4+3][row] = v.w;
    }
    __syncthreads();
    {
      int cl = t >> 4;
      int rs = (t & 15) * 4;
      int c  = c0 + cl;
      int orow = (mode == 0) ? ((c>>4)*32 + (c&15))
               : (mode == 1) ? ((c>>4)*32 + 16 + (c&15))
               : c;
      unsigned long long pk = 0;
      #pragma unroll
      for (int j = 0; j < 4; j++) pk |= (unsigned long long)f2bf(tt[cl][rs+j]) << (16*j);
      *(unsigned long long*)(out + (size_t)orow*R + r0 + rs) = pk;
    }
  } else {
    // ======== x fp32 -> bf16 cast (xb), 4 elems/thread ========
    const int gb = bidx - 12289;              // 0..4095
    size_t base = ((size_t)gb*1024 + t)*4;
    float4 v = *(const float4*)(x + base);
    unsigned long long pk =
        (unsigned long long)f2bf(v.x)
      | ((unsigned long long)f2bf(v.y) << 16)
      | ((unsigned long long)f2bf(v.z) << 32)
      | ((unsigned long long)f2bf(v.w) << 48);
    *(unsigned long long*)(xb + base) = pk;
  }
}

// ================= ring-4 half-K 256x256 GEMM core (R8-proven schedule, FROZEN) =================
__device__ __forceinline__ void stg(const unsigned short* gsrc, int ldg,
                                    unsigned short* Lh, int wave, int lane){
  const int sl = (lane & 3) ^ ((lane >> 3) & 3);   // inverse-swizzled source slot
  #pragma unroll
  for (int j = 0; j < 2; j++){
    int bi = wave*2 + j;
    gld16(gsrc + (size_t)(bi*16 + (lane >> 2))*ldg + sl*8, Lh + bi*512);
  }
}
// A-stage with per-row token indirection (gemm1): per-lane global source, linear LDS dest
__device__ __forceinline__ void stgA_ind(const unsigned short* xb, int tok0, int tok1, int k0,
                                         unsigned short* Lh, int wave, int lane){
  const int sl = (lane & 3) ^ ((lane >> 3) & 3);
  gld16(xb + (size_t)tok0*DIM + k0 + sl*8, Lh + (wave*2+0)*512);
  gld16(xb + (size_t)tok1*DIM + k0 + sl*8, Lh + (wave*2+1)*512);
}
__device__ __forceinline__ bf16x8 frd(const unsigned short* Lh, int r, int g){
  return *(const bf16x8*)(Lh + r*32 + (((g ^ ((r >> 1) & 3))) << 3));
}
template<int MG>
__device__ __forceinline__ void mm16(f32x4 (&acc)[8][4], const bf16x8 (&a)[4], const bf16x8 (&b)[4]){
  #pragma unroll
  for (int i = 0; i < 4; i++)
    #pragma unroll
    for (int n = 0; n < 4; n++)
      acc[MG*4+i][n] = __builtin_amdgcn_mfma_f32_16x16x32_bf16(a[i], b[n], acc[MG*4+i][n], 0, 0, 0);
}

#define STG_A(HH, NS)                                                           \
  { if (EPI == 1) stgA_ind(A, tokA0, tokA1, (HH)*32, NS, wave, lane);           \
    else          stg(Ab + (size_t)(HH)*32, LDG, NS, wave, lane); }

#define HALF_STEP(RS, DOSTG, VMW, HH)                                           \
  {                                                                             \
    unsigned short* LA = lds + (RS)*16384;                                      \
    unsigned short* LB = LA + 8192;                                             \
    unsigned short* NS = lds + (((RS)+3)&3)*16384;                              \
    bf16x8 a[4], b[4];                                                          \
    _Pragma("unroll")                                                           \
    for (int i = 0; i < 4; i++) a[i] = frd(LA, wr*128 + i*16 + l15, g);         \
    _Pragma("unroll")                                                           \
    for (int n = 0; n < 4; n++) b[n] = frd(LB, wc*64 + n*16 + l15, g);          \
    if (DOSTG) STG_A(HH, NS);                                                   \
    HBAR; LG0;                                                                  \
    __builtin_amdgcn_s_setprio(1);  mm16<0>(acc, a, b);                         \
    __builtin_amdgcn_s_setprio(0);                                              \
    HBAR;                                                                       \
    _Pragma("unroll")                                                           \
    for (int i = 0; i < 4; i++) a[i] = frd(LA, wr*128 + (4+i)*16 + l15, g);     \
    if (DOSTG) stg(Bb + (size_t)(HH)*32, LDG, NS + 8192, wave, lane);           \
    HBAR; LG0;                                                                  \
    __builtin_amdgcn_s_setprio(1);  mm16<1>(acc, a, b);                         \
    __builtin_amdgcn_s_setprio(0);                                              \
    if ((VMW) == 4) { asm volatile("s_waitcnt vmcnt(4)" ::: "memory"); }        \
    else if ((VMW) == 0) { asm volatile("s_waitcnt vmcnt(0)" ::: "memory"); }   \
    HBAR;                                                                       \
  }

// EPI 1: gemm1 (A = xb via slot_token indirection; silu fused -> hidden).
// EPI 2: gemm2 K-split -> bf16 partial ks.
template<int KDIM, int LDG, int EPI>
__global__ __launch_bounds__(512, 2) void k_gemm8(
    const unsigned short* __restrict__ A,
    const unsigned short* __restrict__ B,
    unsigned short* __restrict__ Out0,
    unsigned short* __restrict__ Out1,
    const int* __restrict__ slot_token)
{
  constexpr int NH    = KDIM / 32;               // 32 halves
  constexpr int BROWS = (EPI == 1) ? 2*FF : DIM;
  constexpr int LDO   = (EPI == 1) ? FF : DIM;
  __shared__ unsigned short lds[65536];          // 128 KiB = 4 half-slots
  const int id = blockIdx.x;
  const int e  = id & 7;                          // XCD-chunked: expert per XCD
  int t  = id >> 3;
  int ks = 0;
  if (EPI == 2){ ks = t & 1; t >>= 1; }           // K-slice
  const int mt = t % 10, nt = t / 10;
  const int m0 = mt*256, n0 = nt*256;
  const unsigned short* Ab = A + ((size_t)e*CAP   + m0) * LDG + (size_t)ks*KDIM;
  const unsigned short* Bb = B + ((size_t)e*BROWS + n0) * LDG + (size_t)ks*KDIM;
  const int tid = threadIdx.x, wave = tid >> 6, lane = tid & 63;
  const int wr = wave >> 2, wc = wave & 3;        // 2M x 4N waves
  const int g = lane >> 4, l15 = lane & 15;

  int tokA0 = 0, tokA1 = 0;
  if (EPI == 1){
    int r0 = m0 + (wave*2+0)*16 + (lane >> 2);
    int r1 = m0 + (wave*2+1)*16 + (lane >> 2);
    int t0 = slot_token[e*CAP + r0];
    int t1 = slot_token[e*CAP + r1];
    tokA0 = (t0 < 0) ? 0 : t0;                    // empty slot -> token 0 (finite, never read)
    tokA1 = (t1 < 0) ? 0 : t1;
  }

  f32x4 acc[8][4];
  const f32x4 z4 = {0.f,0.f,0.f,0.f};
  #pragma unroll
  for (int i = 0; i < 8; i++)
    #pragma unroll
    for (int n = 0; n < 4; n++) acc[i][n] = z4;

  STG_A(0, lds + 0*16384);
  stg(Bb,      LDG, lds + 0*16384 + 8192, wave, lane);
  STG_A(1, lds + 1*16384);
  stg(Bb + 32, LDG, lds + 1*16384 + 8192, wave, lane);
  STG_A(2, lds + 2*16384);
  stg(Bb + 64, LDG, lds + 2*16384 + 8192, wave, lane);
  asm volatile("s_waitcnt vmcnt(4)" ::: "memory");
  HBAR;

  for (int h = 0; h + 8 <= NH; h += 4){
    HALF_STEP(0, true, -1, h+3);
    HALF_STEP(1, true,  4, h+4);
    HALF_STEP(2, true, -1, h+5);
    HALF_STEP(3, true,  4, h+6);
  }
  HALF_STEP(0, true, -1, NH-1);
  HALF_STEP(1, false, 0, 0);
  HALF_STEP(2, false, -1, 0);
  HALF_STEP(3, false, -1, 0);

  if (EPI == 1){
    unsigned short* H = Out0 + ((size_t)e*CAP + m0 + wr*128) * (size_t)LDO;
    const int hc0 = (n0 + wc*64) >> 1;
    #pragma unroll
    for (int mf = 0; mf < 8; mf++)
      #pragma unroll
      for (int q = 0; q < 4; q++){
        int r = mf*16 + g*4 + q;
        #pragma unroll
        for (int p = 0; p < 2; p++){
          float gg = acc[mf][2*p][q], uu = acc[mf][2*p+1][q];
          float h = gg / (1.f + __expf(-gg)) * uu;
          H[(size_t)r*LDO + hc0 + p*16 + l15] = f2bf(h);
        }
      }
  } else {
    unsigned short* P = (ks ? Out1 : Out0);
    unsigned short* O = P + ((size_t)e*CAP + m0 + wr*128) * (size_t)LDO + n0 + wc*64;
    #pragma unroll
    for (int mf = 0; mf < 8; mf++)
      #pragma unroll
      for (int q = 0; q < 4; q++){
        int r = mf*16 + g*4 + q;
        #pragma unroll
        for (int n = 0; n < 4; n++)
          O[(size_t)r*LDO + n*16 + l15] = f2bf(acc[mf][n][q]);
      }
  }
}

// ---------------- combine: out[t] = sum_k w_k * (P0[slot_k] + P1[slot_k]) ----------------
__global__ __launch_bounds__(256) void k_combine(
    const unsigned short* __restrict__ P0, const unsigned short* __restrict__ P1,
    const int* __restrict__ tok_slots, const float* __restrict__ topw,
    float* __restrict__ out)
{
  const int t = blockIdx.x*2 + (threadIdx.x >> 7);
  const int tid = threadIdx.x & 127;
  const int s0 = tok_slots[t*2+0], s1 = tok_slots[t*2+1];
  const float w0 = topw[t*2+0], w1 = topw[t*2+1];
  float r[8];
  #pragma unroll
  for (int j = 0; j < 8; j++) r[j] = 0.f;
  if (s0 >= 0){
    bf16x8 v0 = *(const bf16x8*)(P0 + (size_t)s0*DIM + tid*8);
    bf16x8 v1 = *(const bf16x8*)(P1 + (size_t)s0*DIM + tid*8);
    #pragma unroll
    for (int j = 0; j < 8; j++)
      r[j] += w0 * (bf2f((unsigned short)v0[j]) + bf2f((unsigned short)v1[j]));
  }
  if (s1 >= 0){
    bf16x8 v0 = *(const bf16x8*)(P0 + (size_t)s1*DIM + tid*8);
    bf16x8 v1 = *(const bf16x8*)(P1 + (size_t)s1*DIM + tid*8);
    #pragma unroll
    for (int j = 0; j < 8; j++)
      r[j] += w1 * (bf2f((unsigned short)v0[j]) + bf2f((unsigned short)v1[j]));
  }
  float4* o = (float4*)(out + (size_t)t*DIM + tid*8);
  o[0] = make_float4(r[0], r[1], r[2], r[3]);
  o[1] = make_float4(r[4], r[5], r[6], r[7]);
}

extern "C" void kernel_launch(void* const* d_in, const int* in_sizes, int n_in,
                              void* d_out, int out_size, void* d_ws, size_t ws_size,
                              hipStream_t stream)
{
  const float* x      = (const float*)d_in[0];
  const float* gate_w = (const float*)d_in[1];
  const float* w_gate = (const float*)d_in[2];
  const float* w_up   = (const float*)d_in[3];
  const float* w_down = (const float*)d_in[4];
  float* out = (float*)d_out;

  uint8_t* ws = (uint8_t*)d_ws;
  int*   topidx       = (int*)ws;               ws += (size_t)N_TOK*2*4;
  float* topw         = (float*)ws;             ws += (size_t)N_TOK*2*4;
  int*   slot_token   = (int*)ws;               ws += (size_t)NSLOT*4;
  int*   tok_slots    = (int*)ws;               ws += (size_t)N_TOK*2*4;
  float* wavepart     = (float*)ws;             ws += (size_t)N_TOK*NEXP*4;
  unsigned short* xb     = (unsigned short*)ws; ws += (size_t)N_TOK*DIM*2;     // 33.6 MB
  unsigned short* P0     = (unsigned short*)ws; ws += (size_t)NSLOT*DIM*2;     // 41.9 MB
  unsigned short* hidden = (unsigned short*)ws; ws += (size_t)NSLOT*FF*2;
  unsigned short* B1     = (unsigned short*)ws; ws += (size_t)NEXP*2*FF*DIM*2; // P1 aliases after gemm1
  unsigned short* wdT    = (unsigned short*)ws; ws += (size_t)NEXP*DIM*FF*2;
  size_t need = (size_t)(ws - (uint8_t*)d_ws);
  if (ws_size < need) return;
  unsigned short* P1 = B1;     // B1 dead after gemm1 consumes it (67 MB >= 42 MB)

  k_router<<<N_TOK/4, 256, 0, stream>>>(x, gate_w, topidx, topw, wavepart);
  // fused: block 0 = scan (+aux, -1 fill); 12288 blocks weight-transpose; 4096 blocks x->bf16
  k_scan_tcv<<<16385, 1024, 0, stream>>>(topidx, wavepart, slot_token, tok_slots,
                                         out + (size_t)N_TOK*DIM,
                                         w_gate, w_up, w_down, B1, wdT, x, xb);
  k_gemm8<DIM, DIM, 1><<<1280, 512, 0, stream>>>(xb, B1, hidden, nullptr, slot_token);
  k_gemm8<DIM, FF, 2><<<640, 512, 0, stream>>>(hidden, wdT, P0, P1, nullptr);
  k_combine<<<N_TOK/2, 256, 0, stream>>>(P0, P1, tok_slots, topw, out);
}

// Round 15
// 422.859 us; speedup vs baseline: 1.2603x; 1.0309x over previous
//
#include <hip/hip_runtime.h>
#include <stdint.h>

#define N_TOK 16384
#define DIM   1024
#define NEXP  8
#define FF    2048
#define CAP   2560
#define NSLOT (NEXP*CAP)   // 20480

using f32x4  = __attribute__((ext_vector_type(4))) float;
using bf16x8 = __attribute__((ext_vector_type(8))) short;

__device__ __forceinline__ unsigned short f2bf(float f){
  union { float f; unsigned u; } c; c.f = f;
  unsigned u = c.u + 0x7FFFu + ((c.u >> 16) & 1u);   // RNE
  return (unsigned short)(u >> 16);
}
__device__ __forceinline__ float bf2f(unsigned short h){
  union { unsigned u; float f; } c; c.u = ((unsigned)h) << 16; return c.f;
}

__device__ __forceinline__ void gld16(const unsigned short* g, unsigned short* l){
  __builtin_amdgcn_global_load_lds((__attribute__((address_space(1))) void*)(void*)g,
                                   (__attribute__((address_space(3))) void*)l,
                                   16, 0, 0);
}

#define HBAR __builtin_amdgcn_s_barrier()
#define LG0  asm volatile("s_waitcnt lgkmcnt(0)" ::: "memory")

// ---------------- router: fp64 logits/softmax; per-token aux partial stores ----------------
__global__ __launch_bounds__(256) void k_router(
    const float* __restrict__ x, const float* __restrict__ gate_w,
    int* __restrict__ topidx, float* __restrict__ topw,
    float* __restrict__ wavepart)
{
  __shared__ float gwT[NEXP][DIM];
  int tid = threadIdx.x;
  for (int i = tid; i < DIM*NEXP; i += 256) gwT[i & 7][i >> 3] = gate_w[i];
  __syncthreads();
  int wave = tid >> 6, lane = tid & 63;
  int t = blockIdx.x * 4 + wave;
  const float* xr = x + (size_t)t * DIM;
  double acc[NEXP];
  #pragma unroll
  for (int e = 0; e < NEXP; e++) acc[e] = 0.0;
  for (int j = 0; j < DIM/64; j++){
    double xv = (double)xr[lane + 64*j];
    #pragma unroll
    for (int e = 0; e < NEXP; e++) acc[e] += xv * (double)gwT[e][lane + 64*j];
  }
  #pragma unroll
  for (int off = 32; off >= 1; off >>= 1){
    #pragma unroll
    for (int e = 0; e < NEXP; e++) acc[e] += __shfl_xor(acc[e], off, 64);
  }
  if (lane == 0){
    double m = acc[0];
    #pragma unroll
    for (int e = 1; e < NEXP; e++) m = fmax(m, acc[e]);
    double p[NEXP], Z = 0.0;
    #pragma unroll
    for (int e = 0; e < NEXP; e++){ p[e] = exp(acc[e] - m); Z += p[e]; }
    double invZ = 1.0 / Z;
    #pragma unroll
    for (int e = 0; e < NEXP; e++) p[e] *= invZ;
    float4* wp = (float4*)(wavepart + (size_t)t*NEXP);
    wp[0] = make_float4((float)p[0], (float)p[1], (float)p[2], (float)p[3]);
    wp[1] = make_float4((float)p[4], (float)p[5], (float)p[6], (float)p[7]);
    int i0 = 0; double p0 = p[0];
    #pragma unroll
    for (int e = 1; e < NEXP; e++) if (p[e] > p0){ p0 = p[e]; i0 = e; }
    int i1 = (i0 == 0) ? 1 : 0; double p1 = p[i1];
    #pragma unroll
    for (int e = 0; e < NEXP; e++) if (e != i0 && p[e] > p1){ p1 = p[e]; i1 = e; }
    double s = p0 + p1;
    topidx[t*2+0] = i0; topidx[t*2+1] = i1;
    topw [t*2+0] = (float)(p0/s); topw[t*2+1] = (float)(p1/s);
  }
}

// ---- fused: block 0 = scan (+aux, -1 fill); 1..12288 = weight transpose; rest = x->bf16 ----
__global__ __launch_bounds__(1024) void k_scan_tcv(
    const int* __restrict__ topidx, const float* __restrict__ wavepart,
    int* __restrict__ slot_token, int* __restrict__ tok_slots,
    float* __restrict__ aux_out,
    const float* __restrict__ wg, const float* __restrict__ wu, const float* __restrict__ wd,
    unsigned short* __restrict__ B1, unsigned short* __restrict__ wdT,
    const float* __restrict__ x, unsigned short* __restrict__ xb)
{
  __shared__ uint8_t smem[32768];
  const int t = threadIdx.x;
  const int bidx = blockIdx.x;

  if (bidx == 0){
    int (*sc)[NEXP] = (int(*)[NEXP])smem;
    const int base_i = t * 32;
    int ids[32];
    #pragma unroll
    for (int j = 0; j < 32; j++) ids[j] = topidx[base_i + j];
    int b[NEXP];
    #pragma unroll
    for (int e = 0; e < NEXP; e++) b[e] = 0;
    #pragma unroll
    for (int j = 0; j < 32; j++){
      #pragma unroll
      for (int e = 0; e < NEXP; e++) if (ids[j] == e) b[e]++;
    }
    #pragma unroll
    for (int e = 0; e < NEXP; e++) sc[t][e] = b[e];
    __syncthreads();
    for (int off = 1; off < 1024; off <<= 1){
      int tmp[NEXP];
      #pragma unroll
      for (int e = 0; e < NEXP; e++) tmp[e] = (t >= off) ? sc[t-off][e] : 0;
      __syncthreads();
      #pragma unroll
      for (int e = 0; e < NEXP; e++) sc[t][e] += tmp[e];
      __syncthreads();
    }
    int myb[NEXP];
    #pragma unroll
    for (int e = 0; e < NEXP; e++) myb[e] = sc[t][e] - b[e];
    int cnt[NEXP];
    #pragma unroll
    for (int e = 0; e < NEXP; e++) cnt[e] = sc[1023][e];
    #pragma unroll
    for (int j = 0; j < 32; j++){
      int slot = -1;
      #pragma unroll
      for (int e = 0; e < NEXP; e++){
        if (ids[j] == e){
          int r = myb[e]; myb[e] = r + 1;
          if (r < CAP){
            slot = e*CAP + r;
            slot_token[slot] = (base_i + j) >> 1;
          }
        }
      }
      tok_slots[base_i + j] = slot;
    }
    for (int idx = t; idx < NSLOT; idx += 1024){
      int e2 = idx / CAP, r2 = idx - e2*CAP;
      if (r2 >= cnt[e2]) slot_token[idx] = -1;
    }
    __syncthreads();
    float pe[NEXP];
    #pragma unroll
    for (int e = 0; e < NEXP; e++) pe[e] = 0.f;
    for (int i = t; i < N_TOK; i += 1024){
      const float4* pr = (const float4*)(wavepart + (size_t)i*NEXP);
      float4 v0 = pr[0], v1 = pr[1];
      pe[0] += v0.x; pe[1] += v0.y; pe[2] += v0.z; pe[3] += v0.w;
      pe[4] += v1.x; pe[5] += v1.y; pe[6] += v1.z; pe[7] += v1.w;
    }
    #pragma unroll
    for (int off = 32; off >= 1; off >>= 1){
      #pragma unroll
      for (int e = 0; e < NEXP; e++) pe[e] += __shfl_xor(pe[e], off, 64);
    }
    __syncthreads();
    float* scf = (float*)smem;
    const int wv = t >> 6, ln = t & 63;
    if (ln == 0){
      #pragma unroll
      for (int e = 0; e < NEXP; e++) scf[wv*NEXP + e] = pe[e];
    }
    __syncthreads();
    if (t == 0){
      float aux = 0.f;
      #pragma unroll
      for (int e = 0; e < NEXP; e++){
        float P = 0.f;
        for (int w = 0; w < 16; w++) P += scf[w*NEXP + e];
        P /= (float)N_TOK;
        float f = (float)cnt[e] / ((float)(N_TOK*2) + 1e-9f);
        aux += f * P;
      }
      aux_out[0] = (float)NEXP * aux * 0.01f;
    }
  } else if (bidx <= 12288){
    float (*tt)[65] = (float(*)[65])smem;
    const int bid = bidx - 1;
    const int z = bid >> 9, rem = bid & 511;
    const int mode = z >> 3, e = z & 7;
    const float* in; unsigned short* out; int R, C, ct, rt;
    if (mode < 2){
      in  = (mode == 0 ? wg : wu) + (size_t)e * DIM * FF;
      out = B1 + (size_t)e * 2 * FF * DIM;
      R = DIM; C = FF; ct = rem & 31; rt = rem >> 5;
    } else {
      in  = wd + (size_t)e * FF * DIM;
      out = wdT + (size_t)e * DIM * FF;
      R = FF; C = DIM; ct = rem >> 5; rt = rem & 31;
    }
    const int c0 = ct * 64, r0 = rt * 64;
    {
      int row = t >> 4, c4 = t & 15;
      float4 v = *(const float4*)(in + (size_t)(r0 + row)*C + c0 + c4*4);
      tt[c4*4+0][row] = v.x; tt[c4*4+1][row] = v.y;
      tt[c4*4+2][row] = v.z; tt[c4*4+3][row] = v.w;
    }
    __syncthreads();
    {
      int cl = t >> 4;
      int rs = (t & 15) * 4;
      int c  = c0 + cl;
      int orow = (mode == 0) ? ((c>>4)*32 + (c&15))
               : (mode == 1) ? ((c>>4)*32 + 16 + (c&15))
               : c;
      unsigned long long pk = 0;
      #pragma unroll
      for (int j = 0; j < 4; j++) pk |= (unsigned long long)f2bf(tt[cl][rs+j]) << (16*j);
      *(unsigned long long*)(out + (size_t)orow*R + r0 + rs) = pk;
    }
  } else {
    const int gb = bidx - 12289;
    size_t base = ((size_t)gb*1024 + t)*4;
    float4 v = *(const float4*)(x + base);
    unsigned long long pk =
        (unsigned long long)f2bf(v.x)
      | ((unsigned long long)f2bf(v.y) << 16)
      | ((unsigned long long)f2bf(v.z) << 32)
      | ((unsigned long long)f2bf(v.w) << 48);
    *(unsigned long long*)(xb + base) = pk;
  }
}

// ================= m-split 8-region 256x256 GEMM (m201-style quadrant phases) =================
// LDS: 8 regions x 16 KiB; region (4*kt+type)&7; type 0=A-lo 1=A-hi 2=B-lo 3=B-hi (128 rows x 64 k).
// Swizzle: store kslot=(lane&7)^(lane>>3) at phys slot lane&7; read phys = kslot^(r&7), r&7 = l15&7.
#define FRD(R_, RR, KS) (*(const bf16x8*)((R_) + (RR)*64 + ((((KS)) ^ l7) << 3)))

#define STGH(TYPE, KT2) {                                                          \
    unsigned short* R_ = lds + ((((KT2)&1)*4 + (TYPE)))*8192;                      \
    if ((TYPE) < 2){                                                               \
      if (EPI == 1){                                                               \
        gld16(Axb + aoff[(TYPE)&1][0] + (KT2)*64, R_ + (wave*8)*64);               \
        gld16(Axb + aoff[(TYPE)&1][1] + (KT2)*64, R_ + (64 + wave*8)*64);          \
      } else {                                                                     \
        gld16(a00 + (size_t)(((TYPE)&1)*128 +  0)*LDG + (KT2)*64, R_ + (wave*8)*64);      \
        gld16(a00 + (size_t)(((TYPE)&1)*128 + 64)*LDG + (KT2)*64, R_ + (64 + wave*8)*64); \
      }                                                                            \
    } else {                                                                       \
      gld16(b00 + (size_t)(((TYPE)&1)*128 +  0)*LDG + (KT2)*64, R_ + (wave*8)*64);        \
      gld16(b00 + (size_t)(((TYPE)&1)*128 + 64)*LDG + (KT2)*64, R_ + (64 + wave*8)*64);   \
    } }

#define MM8(AM, AN, AV, BV)                                                        \
  _Pragma("unroll")                                                                \
  for (int f = 0; f < 4; f++)                                                      \
    _Pragma("unroll")                                                              \
    for (int n = 0; n < 2; n++)                                                    \
      _Pragma("unroll")                                                            \
      for (int kk = 0; kk < 2; kk++)                                               \
        acc[(AM)+f][(AN)+n] = __builtin_amdgcn_mfma_f32_16x16x32_bf16(             \
            AV[f*2+kk], BV[n*2+kk], acc[(AM)+f][(AN)+n], 0, 0, 0);

// EPI 1: gemm1 (A = xb via slot_token indirection; silu fused -> hidden).
// EPI 2: gemm2 K-split -> bf16 partial ks.
template<int KDIM, int LDG, int EPI>
__global__ __launch_bounds__(512, 2) void k_gemm8(
    const unsigned short* __restrict__ A,
    const unsigned short* __restrict__ B,
    unsigned short* __restrict__ Out0,
    unsigned short* __restrict__ Out1,
    const int* __restrict__ slot_token)
{
  constexpr int NT    = KDIM / 64;               // K-tiles (16)
  constexpr int BROWS = (EPI == 1) ? 2*FF : DIM;
  constexpr int LDO   = (EPI == 1) ? FF : DIM;
  __shared__ unsigned short lds[65536];          // 8 regions x 8192 shorts
  const int id = blockIdx.x;
  const int e  = id & 7;
  int t  = id >> 3;
  int ks = 0;
  if (EPI == 2){ ks = t & 1; t >>= 1; }
  const int mt = t % 10, nt = t / 10;
  const int m0 = mt*256, n0 = nt*256;
  const unsigned short* Ab = A + ((size_t)e*CAP   + m0) * LDG + (size_t)ks*KDIM;
  const unsigned short* Bb = B + ((size_t)e*BROWS + n0) * LDG + (size_t)ks*KDIM;
  const int tid = threadIdx.x, wave = tid >> 6, lane = tid & 63;
  const int wr = wave >> 2, wc = wave & 3;        // 2M x 4N waves, 128x64 out each
  const int g = lane >> 4, l15 = lane & 15, l7 = l15 & 7;
  const int srow = lane >> 3, sslot = lane & 7;
  const int kslot_src = sslot ^ srow;

  // staging source bases
  const unsigned short* Axb = A + (size_t)kslot_src*8;            // EPI1
  unsigned int aoff[2][2];                                        // EPI1: tok*DIM per (half,j)
  const unsigned short* a00 = Ab + (size_t)(wave*8 + srow)*LDG + kslot_src*8;  // EPI2
  const unsigned short* b00 = Bb + (size_t)(wave*8 + srow)*LDG + kslot_src*8;
  if (EPI == 1){
    #pragma unroll
    for (int ah = 0; ah < 2; ah++)
      #pragma unroll
      for (int j = 0; j < 2; j++){
        int row = m0 + ah*128 + j*64 + wave*8 + srow;
        int tk = slot_token[e*CAP + row];
        aoff[ah][j] = (unsigned)((tk < 0 ? 0 : tk) * DIM);
      }
  }

  f32x4 acc[8][4];
  const f32x4 z4 = {0.f,0.f,0.f,0.f};
  #pragma unroll
  for (int i = 0; i < 8; i++)
    #pragma unroll
    for (int n = 0; n < 4; n++) acc[i][n] = z4;

  // prologue: stage halves 0..6 (14 gld); vmcnt(6) -> halves 0..3 landed
  STGH(0,0); STGH(1,0); STGH(2,0); STGH(3,0);
  STGH(0,1); STGH(1,1); STGH(2,1);
  asm volatile("s_waitcnt vmcnt(6)" ::: "memory");
  HBAR;

  for (int kt = 0; kt < NT; ++kt){
    const int b0 = (kt & 1)*4;
    unsigned short* RA = lds + (b0 + wr)*8192;            // wave's A region
    unsigned short* RB = lds + (b0 + 2 + (wc >> 1))*8192; // wave's B region
    const int nb = (wc & 1)*64;
    bf16x8 a0[8], a1[8], bv[4], b2[4];

    // ---- q0: read a0 + b; stage B-hi(kt+1); MFMA m0n0 ----
    #pragma unroll
    for (int f = 0; f < 4; f++)
      #pragma unroll
      for (int kk = 0; kk < 2; kk++)
        a0[f*2+kk] = FRD(RA, f*16 + l15, kk*4 + g);
    #pragma unroll
    for (int n = 0; n < 2; n++)
      #pragma unroll
      for (int kk = 0; kk < 2; kk++)
        bv[n*2+kk] = FRD(RB, nb + n*16 + l15, kk*4 + g);
    if (kt + 1 < NT) STGH(3, kt+1);
    HBAR; LG0;
    __builtin_amdgcn_s_setprio(1);  MM8(0, 0, a0, bv);  __builtin_amdgcn_s_setprio(0);

    // ---- q1: read a1; stage A-lo(kt+2); MFMA m1n0 ----
    #pragma unroll
    for (int f = 0; f < 4; f++)
      #pragma unroll
      for (int kk = 0; kk < 2; kk++)
        a1[f*2+kk] = FRD(RA, 64 + f*16 + l15, kk*4 + g);
    if (kt + 2 < NT) STGH(0, kt+2);
    HBAR; LG0;
    __builtin_amdgcn_s_setprio(1);  MM8(4, 0, a1, bv);  __builtin_amdgcn_s_setprio(0);

    // ---- q2: read b2; stage A-hi(kt+2); MFMA m1n1 ----
    #pragma unroll
    for (int n = 0; n < 2; n++)
      #pragma unroll
      for (int kk = 0; kk < 2; kk++)
        b2[n*2+kk] = FRD(RB, nb + 32 + n*16 + l15, kk*4 + g);
    if (kt + 2 < NT) STGH(1, kt+2);
    HBAR; LG0;
    __builtin_amdgcn_s_setprio(1);  MM8(4, 2, a1, b2);  __builtin_amdgcn_s_setprio(0);

    // ---- q3: stage B-lo(kt+2); MFMA m0n1; end-of-ktile wait+publish ----
    if (kt + 2 < NT) STGH(2, kt+2);
    __builtin_amdgcn_s_setprio(1);  MM8(0, 2, a0, b2);  __builtin_amdgcn_s_setprio(0);
    if (kt <= NT-3)      { asm volatile("s_waitcnt vmcnt(6)" ::: "memory"); }
    else if (kt == NT-2) { asm volatile("s_waitcnt vmcnt(0)" ::: "memory"); }
    HBAR;
  }

  if (EPI == 1){
    unsigned short* H = Out0 + ((size_t)e*CAP + m0 + wr*128) * (size_t)LDO;
    const int hc0 = (n0 + wc*64) >> 1;
    #pragma unroll
    for (int mf = 0; mf < 8; mf++)
      #pragma unroll
      for (int q = 0; q < 4; q++){
        int r = mf*16 + g*4 + q;
        #pragma unroll
        for (int p = 0; p < 2; p++){
          float gg = acc[mf][2*p][q], uu = acc[mf][2*p+1][q];
          float h = gg / (1.f + __expf(-gg)) * uu;
          H[(size_t)r*LDO + hc0 + p*16 + l15] = f2bf(h);
        }
      }
  } else {
    unsigned short* P = (ks ? Out1 : Out0);
    unsigned short* O = P + ((size_t)e*CAP + m0 + wr*128) * (size_t)LDO + n0 + wc*64;
    #pragma unroll
    for (int mf = 0; mf < 8; mf++)
      #pragma unroll
      for (int q = 0; q < 4; q++){
        int r = mf*16 + g*4 + q;
        #pragma unroll
        for (int n = 0; n < 4; n++)
          O[(size_t)r*LDO + n*16 + l15] = f2bf(acc[mf][n][q]);
      }
  }
}

// ---------------- combine: out[t] = sum_k w_k * (P0[slot_k] + P1[slot_k]) ----------------
__global__ __launch_bounds__(256) void k_combine(
    const unsigned short* __restrict__ P0, const unsigned short* __restrict__ P1,
    const int* __restrict__ tok_slots, const float* __restrict__ topw,
    float* __restrict__ out)
{
  const int t = blockIdx.x*2 + (threadIdx.x >> 7);
  const int tid = threadIdx.x & 127;
  const int s0 = tok_slots[t*2+0], s1 = tok_slots[t*2+1];
  const float w0 = topw[t*2+0], w1 = topw[t*2+1];
  float r[8];
  #pragma unroll
  for (int j = 0; j < 8; j++) r[j] = 0.f;
  if (s0 >= 0){
    bf16x8 v0 = *(const bf16x8*)(P0 + (size_t)s0*DIM + tid*8);
    bf16x8 v1 = *(const bf16x8*)(P1 + (size_t)s0*DIM + tid*8);
    #pragma unroll
    for (int j = 0; j < 8; j++)
      r[j] += w0 * (bf2f((unsigned short)v0[j]) + bf2f((unsigned short)v1[j]));
  }
  if (s1 >= 0){
    bf16x8 v0 = *(const bf16x8*)(P0 + (size_t)s1*DIM + tid*8);
    bf16x8 v1 = *(const bf16x8*)(P1 + (size_t)s1*DIM + tid*8);
    #pragma unroll
    for (int j = 0; j < 8; j++)
      r[j] += w1 * (bf2f((unsigned short)v0[j]) + bf2f((unsigned short)v1[j]));
  }
  float4* o = (float4*)(out + (size_t)t*DIM + tid*8);
  o[0] = make_float4(r[0], r[1], r[2], r[3]);
  o[1] = make_float4(r[4], r[5], r[6], r[7]);
}

extern "C" void kernel_launch(void* const* d_in, const int* in_sizes, int n_in,
                              void* d_out, int out_size, void* d_ws, size_t ws_size,
                              hipStream_t stream)
{
  const float* x      = (const float*)d_in[0];
  const float* gate_w = (const float*)d_in[1];
  const float* w_gate = (const float*)d_in[2];
  const float* w_up   = (const float*)d_in[3];
  const float* w_down = (const float*)d_in[4];
  float* out = (float*)d_out;

  uint8_t* ws = (uint8_t*)d_ws;
  int*   topidx       = (int*)ws;               ws += (size_t)N_TOK*2*4;
  float* topw         = (float*)ws;             ws += (size_t)N_TOK*2*4;
  int*   slot_token   = (int*)ws;               ws += (size_t)NSLOT*4;
  int*   tok_slots    = (int*)ws;               ws += (size_t)N_TOK*2*4;
  float* wavepart     = (float*)ws;             ws += (size_t)N_TOK*NEXP*4;
  unsigned short* xb     = (unsigned short*)ws; ws += (size_t)N_TOK*DIM*2;
  unsigned short* P0     = (unsigned short*)ws; ws += (size_t)NSLOT*DIM*2;
  unsigned short* hidden = (unsigned short*)ws; ws += (size_t)NSLOT*FF*2;
  unsigned short* B1     = (unsigned short*)ws; ws += (size_t)NEXP*2*FF*DIM*2;
  unsigned short* wdT    = (unsigned short*)ws; ws += (size_t)NEXP*DIM*FF*2;
  size_t need = (size_t)(ws - (uint8_t*)d_ws);
  if (ws_size < need) return;
  unsigned short* P1 = B1;     // B1 dead after gemm1 consumes it

  k_router<<<N_TOK/4, 256, 0, stream>>>(x, gate_w, topidx, topw, wavepart);
  k_scan_tcv<<<16385, 1024, 0, stream>>>(topidx, wavepart, slot_token, tok_slots,
                                         out + (size_t)N_TOK*DIM,
                                         w_gate, w_up, w_down, B1, wdT, x, xb);
  k_gemm8<DIM, DIM, 1><<<1280, 512, 0, stream>>>(xb, B1, hidden, nullptr, slot_token);
  k_gemm8<DIM, FF, 2><<<640, 512, 0, stream>>>(hidden, wdT, P0, P1, nullptr);
  k_combine<<<N_TOK/2, 256, 0, stream>>>(P0, P1, tok_slots, topw, out);
}